// Round 7
// baseline (20284.029 us; speedup 1.0000x reference)
//
#include <hip/hip_runtime.h>
#include <cstdint>
#include <cstddef>

// ---------------------------------------------------------------------------
// GatedGIN forward. Inputs bf16-or-f32 (runtime probe), OUTPUT = FLOAT32
// (Round-6 forensics: comparator reads f32; bf16 stores aliased two nodes
// per slot and overlapped later outputs -> the invariant 1.1289 signature).
// fp32 compute, bf16 activation storage. Workspace ~94 MB (fits).
// ---------------------------------------------------------------------------

static __device__ __forceinline__ float bf2f(uint16_t u) {
  return __uint_as_float(((uint32_t)u) << 16);
}
static __device__ __forceinline__ uint16_t f2b(float f) {
  uint32_t x = __float_as_uint(f);
  return (uint16_t)((x + 0x7FFFu + ((x >> 16) & 1u)) >> 16);
}
static __device__ __forceinline__ float sigmoidf_(float v) {
  return 1.f / (1.f + __expf(-v));
}

// ---------------- dtype probe ----------------
__global__ void k_detect(const uint32_t* __restrict__ u, int* __restrict__ flag) {
  int lane = threadIdx.x;  // 64 threads
  uint32_t low = u[lane] & 0xFFFFu;
  uint32_t e = (low >> 7) & 0xFFu;
  bool pass = (e == 0) || (e >= 110 && e <= 141);
  unsigned long long b = __ballot(pass);
  if (lane == 0) *flag = (__popcll(b) >= 32) ? 1 : 0;
}

// ---------------- upcast weights to f32 workspace ----------------
struct CvtDesc {
  const void* src[18];
  int off[19];
};

__global__ void k_cvtw(CvtDesc c, float* __restrict__ wbase,
                       const int* __restrict__ flag, int total) {
  int gid = blockIdx.x * 256 + threadIdx.x;
  if (gid >= total) return;
  int t = 0;
#pragma unroll
  for (int i = 1; i < 18; i++)
    if (gid >= c.off[i]) t = i;
  int local = gid - c.off[t];
  float v;
  if (*flag) v = bf2f(((const uint16_t*)c.src[t])[local]);
  else       v = ((const float*)c.src[t])[local];
  wbase[gid] = v;
}

__global__ void k_cvt_feat(const void* __restrict__ src, uint16_t* __restrict__ dst,
                           int n, const int* __restrict__ flag) {
  int i = blockIdx.x * 256 + threadIdx.x;
  if (i >= n) return;
  if (*flag) dst[i] = ((const uint16_t*)src)[i];
  else       dst[i] = f2b(((const float*)src)[i]);
}

__global__ void k_zero_i(int* __restrict__ p, int n) {
  int i = blockIdx.x * 256 + threadIdx.x;
  if (i < n) p[i] = 0;
}

__global__ void k_zero_f(float* __restrict__ p, int n) {
  int i = blockIdx.x * 256 + threadIdx.x;
  if (i < n) p[i] = 0.f;
}

// ---------------- CSR build ----------------
__global__ void k_hist(const int* __restrict__ dst, int* __restrict__ deg, int E) {
  int e = blockIdx.x * 256 + threadIdx.x;
  if (e < E) atomicAdd(&deg[dst[e]], 1);
}

__global__ void k_scan1(const int* __restrict__ deg, int* __restrict__ bsum, int n) {
  __shared__ int red[256];
  int t = threadIdx.x;
  int base = blockIdx.x * 1024;
  int s = 0;
#pragma unroll
  for (int i = 0; i < 4; i++) {
    int idx = base + i * 256 + t;
    if (idx < n) s += deg[idx];
  }
  red[t] = s;
  __syncthreads();
  for (int off = 128; off > 0; off >>= 1) {
    if (t < off) red[t] += red[t + off];
    __syncthreads();
  }
  if (t == 0) bsum[blockIdx.x] = red[0];
}

__global__ void k_scan2(int* bsum, int nb, int* rowptr, int n) {
  if (threadIdx.x == 0 && blockIdx.x == 0) {
    int run = 0;
    for (int b = 0; b < nb; b++) {
      int v = bsum[b];
      bsum[b] = run;
      run += v;
    }
    rowptr[n] = run;  // == E
  }
}

__global__ void k_scan3(const int* __restrict__ deg, const int* __restrict__ bsum,
                        int* __restrict__ rowptr, int* __restrict__ cursor, int n) {
  __shared__ int lds[256];
  int t = threadIdx.x;
  int base = blockIdx.x * 1024 + t * 4;
  int v0 = 0, v1 = 0, v2 = 0, v3 = 0;
  if (base + 0 < n) v0 = deg[base + 0];
  if (base + 1 < n) v1 = deg[base + 1];
  if (base + 2 < n) v2 = deg[base + 2];
  if (base + 3 < n) v3 = deg[base + 3];
  int s = v0 + v1 + v2 + v3;
  lds[t] = s;
  __syncthreads();
  for (int off = 1; off < 256; off <<= 1) {
    int u = (t >= off) ? lds[t - off] : 0;
    __syncthreads();
    lds[t] += u;
    __syncthreads();
  }
  int run = lds[t] - s + bsum[blockIdx.x];
  if (base + 0 < n) { rowptr[base + 0] = run; cursor[base + 0] = run; run += v0; }
  if (base + 1 < n) { rowptr[base + 1] = run; cursor[base + 1] = run; run += v1; }
  if (base + 2 < n) { rowptr[base + 2] = run; cursor[base + 2] = run; run += v2; }
  if (base + 3 < n) { rowptr[base + 3] = run; cursor[base + 3] = run; run += v3; }
}

__global__ void k_scatter(const int* __restrict__ dst, const int* __restrict__ src,
                          const void* __restrict__ w, int* __restrict__ cursor,
                          int* __restrict__ csr_src, float* __restrict__ csr_w,
                          const int* __restrict__ flag, int E) {
  int e = blockIdx.x * 256 + threadIdx.x;
  if (e < E) {
    int d = dst[e];
    int pos = atomicAdd(&cursor[d], 1);
    csr_src[pos] = src[e];
    float wv;
    if (*flag) wv = bf2f(((const uint16_t*)w)[e]);
    else       wv = ((const float*)w)[e];
    csr_w[pos] = wv;
  }
}

// ---------------- SpMM gather ----------------
__global__ void k_spmm(const uint16_t* __restrict__ x, const int* __restrict__ rowptr,
                       const int* __restrict__ csr_src, const float* __restrict__ csr_w,
                       uint16_t* __restrict__ agg, int n) {
  int node = blockIdx.x * 2 + (threadIdx.x >> 7);
  int f = threadIdx.x & 127;
  if (node >= n) return;
  int p0 = rowptr[node], p1 = rowptr[node + 1];
  float acc = 0.f;
  int p = p0;
  for (; p + 1 < p1; p += 2) {
    int s0 = csr_src[p], s1 = csr_src[p + 1];
    float w0 = csr_w[p], w1 = csr_w[p + 1];
    acc = fmaf(w0, bf2f(x[(size_t)s0 * 128 + f]), acc);
    acc = fmaf(w1, bf2f(x[(size_t)s1 * 128 + f]), acc);
  }
  if (p < p1) acc = fmaf(csr_w[p], bf2f(x[(size_t)csr_src[p] * 128 + f]), acc);
  agg[(size_t)node * 128 + f] = f2b(acc);
}

// ---------------- SIMPLE matmul: C = act(A[N,128] @ W[128,128]^T + b) ------
template <int EPI>
__launch_bounds__(256)
__global__ void k_mms(const uint16_t* __restrict__ A, const float* __restrict__ W,
                      const float* __restrict__ bias, uint16_t* __restrict__ C,
                      int nrows) {
  __shared__ float ar[8][128];
  __shared__ float sq[8][33];
  int tid = threadIdx.x;
  int r0 = blockIdx.x * 8;
  {
    int q = tid * 4;
    int row = q >> 7, k = q & 127;
    int gr = r0 + row;
#pragma unroll
    for (int j = 0; j < 4; j++)
      ar[row][k + j] = (gr < nrows) ? bf2f(A[(size_t)gr * 128 + k + j]) : 0.f;
  }
  __syncthreads();
  int rl = tid >> 5;
  int cg = tid & 31;
  float v[4];
  float ss = 0.f;
#pragma unroll
  for (int cc = 0; cc < 4; cc++) {
    int col = cg * 4 + cc;
    const float* wr = W + (size_t)col * 128;
    float acc = 0.f;
    for (int k4 = 0; k4 < 128; k4 += 4) {
      float4 w4 = *reinterpret_cast<const float4*>(&wr[k4]);
      acc = fmaf(ar[rl][k4 + 0], w4.x, acc);
      acc = fmaf(ar[rl][k4 + 1], w4.y, acc);
      acc = fmaf(ar[rl][k4 + 2], w4.z, acc);
      acc = fmaf(ar[rl][k4 + 3], w4.w, acc);
    }
    float t = fmaxf(acc + bias[col], 0.f);
    v[cc] = t;
    ss = fmaf(t, t, ss);
  }
  if (EPI == 2) {
    sq[rl][cg] = ss;
    __syncthreads();
    float s = 0.f;
    for (int j = 0; j < 32; j++) s += sq[rl][j];
    float sc = rsqrtf(1.f + s);
#pragma unroll
    for (int cc = 0; cc < 4; cc++) v[cc] *= sc;
  }
  int gr = r0 + rl;
  if (gr < nrows) {
#pragma unroll
    for (int cc = 0; cc < 4; cc++)
      C[(size_t)gr * 128 + cg * 4 + cc] = f2b(v[cc]);
  }
}

// ---------------- SIMPLE fused GRU ----------------
__launch_bounds__(256)
__global__ void k_grus(const uint16_t* __restrict__ aggb, const uint16_t* __restrict__ xb,
                       const float* __restrict__ wih, const float* __restrict__ whh,
                       const float* __restrict__ bih, const float* __restrict__ bhh,
                       uint16_t* __restrict__ hb, int n) {
  __shared__ float ar[8][128];
  __shared__ float xr[8][128];
  int tid = threadIdx.x;
  int r0 = blockIdx.x * 8;
  {
    int q = tid * 4;
    int row = q >> 7, k = q & 127;
    int gr = r0 + row;
#pragma unroll
    for (int j = 0; j < 4; j++) {
      ar[row][k + j] = (gr < n) ? bf2f(aggb[(size_t)gr * 128 + k + j]) : 0.f;
      xr[row][k + j] = (gr < n) ? bf2f(xb[(size_t)gr * 128 + k + j]) : 0.f;
    }
  }
  __syncthreads();
  int rl = tid >> 5;
  int cg = tid & 31;
  int gr = r0 + rl;
#pragma unroll
  for (int cc = 0; cc < 4; cc++) {
    int col = cg * 4 + cc;
    const float* wir = wih + (size_t)col * 128;
    const float* wiz = wir + 128 * 128;
    const float* win = wiz + 128 * 128;
    const float* whr = whh + (size_t)col * 128;
    const float* whz = whr + 128 * 128;
    const float* whn = whz + 128 * 128;
    float air = 0.f, aiz = 0.f, ain = 0.f, ahr = 0.f, ahz = 0.f, ahn = 0.f;
    for (int k4 = 0; k4 < 128; k4 += 4) {
      float4 a4 = *reinterpret_cast<const float4*>(&ar[rl][k4]);
      float4 x4 = *reinterpret_cast<const float4*>(&xr[rl][k4]);
      float4 w;
      w = *reinterpret_cast<const float4*>(&wir[k4]);
      air = fmaf(a4.x, w.x, air); air = fmaf(a4.y, w.y, air);
      air = fmaf(a4.z, w.z, air); air = fmaf(a4.w, w.w, air);
      w = *reinterpret_cast<const float4*>(&wiz[k4]);
      aiz = fmaf(a4.x, w.x, aiz); aiz = fmaf(a4.y, w.y, aiz);
      aiz = fmaf(a4.z, w.z, aiz); aiz = fmaf(a4.w, w.w, aiz);
      w = *reinterpret_cast<const float4*>(&win[k4]);
      ain = fmaf(a4.x, w.x, ain); ain = fmaf(a4.y, w.y, ain);
      ain = fmaf(a4.z, w.z, ain); ain = fmaf(a4.w, w.w, ain);
      w = *reinterpret_cast<const float4*>(&whr[k4]);
      ahr = fmaf(x4.x, w.x, ahr); ahr = fmaf(x4.y, w.y, ahr);
      ahr = fmaf(x4.z, w.z, ahr); ahr = fmaf(x4.w, w.w, ahr);
      w = *reinterpret_cast<const float4*>(&whz[k4]);
      ahz = fmaf(x4.x, w.x, ahz); ahz = fmaf(x4.y, w.y, ahz);
      ahz = fmaf(x4.z, w.z, ahz); ahz = fmaf(x4.w, w.w, ahz);
      w = *reinterpret_cast<const float4*>(&whn[k4]);
      ahn = fmaf(x4.x, w.x, ahn); ahn = fmaf(x4.y, w.y, ahn);
      ahn = fmaf(x4.z, w.z, ahn); ahn = fmaf(x4.w, w.w, ahn);
    }
    float rr = sigmoidf_((air + bih[col]) + (ahr + bhh[col]));
    float zz = sigmoidf_((aiz + bih[128 + col]) + (ahz + bhh[128 + col]));
    float nn = tanhf(fmaf(rr, ahn + bhh[256 + col], ain + bih[256 + col]));
    float xv = xr[rl][col];
    if (gr < n)
      hb[(size_t)gr * 128 + col] = f2b(fmaf(zz, xv - nn, nn));
  }
}

// ---------------- SIMPLE head: one thread per node, FLOAT32 output ---------
template <int C>
__global__ void k_heads(const uint16_t* __restrict__ hh, const float* __restrict__ w2,
                        const float* __restrict__ b2,
                        float* __restrict__ out_log, float* __restrict__ out_soft,
                        int n) {
  int node = blockIdx.x * 256 + threadIdx.x;
  if (node >= n) return;
  const uint16_t* row = hh + (size_t)node * 128;
  float lg[C];
#pragma unroll
  for (int c = 0; c < C; c++) lg[c] = b2[c];
  for (int k = 0; k < 128; k++) {
    float xv = bf2f(row[k]);
#pragma unroll
    for (int c = 0; c < C; c++) lg[c] = fmaf(xv, w2[c * 128 + k], lg[c]);
  }
  float m = lg[0];
#pragma unroll
  for (int c = 1; c < C; c++) m = fmaxf(m, lg[c]);
  float s = 0.f;
  float e[C];
#pragma unroll
  for (int c = 0; c < C; c++) { e[c] = __expf(lg[c] - m); s += e[c]; }
  float ls = __logf(s);
  float inv = 1.f / s;
#pragma unroll
  for (int c = 0; c < C; c++) {
    out_log[(size_t)node * C + c] = lg[c] - m - ls;
    out_soft[(size_t)node * C + c] = e[c] * inv;
  }
}

// ---------------------------------------------------------------------------
extern "C" void kernel_launch(void* const* d_in, const int* in_sizes, int n_in,
                              void* d_out, int out_size, void* d_ws, size_t ws_size,
                              hipStream_t stream) {
  const int N = in_sizes[0] / 128;   // 100000
  const int E = in_sizes[2];         // 1600000

  static const int wn[18] = {16384, 128, 49152, 384, 49152, 384,
                             147456, 147456, 1152, 1152, 49152, 384,
                             256, 2, 768, 6, 2688, 21};
  CvtDesc cd;
  int off = 0;
  for (int i = 0; i < 18; i++) {
    cd.src[i] = d_in[3 + i];
    cd.off[i] = off;
    off += wn[i];
  }
  cd.off[18] = off;
  const int wtotal = off;  // 466077

  // ---- workspace bump allocator (~94 MB) ----
  char* p = (char*)d_ws;
  size_t used = 0;
  auto alloc = [&](size_t bytes) -> char* {
    char* r = p;
    size_t b = (bytes + 255) & ~(size_t)255;
    p += b;
    used += b;
    return r;
  };
  int*      flag   = (int*)alloc(256);
  float*    wbase  = (float*)alloc((size_t)wtotal * 4);
  uint16_t* xb     = (uint16_t*)alloc((size_t)N * 128 * 2);
  uint16_t* aggb   = (uint16_t*)alloc((size_t)N * 128 * 2);
  uint16_t* hb     = (uint16_t*)alloc((size_t)N * 128 * 2);
  int*      deg    = (int*)alloc((size_t)N * 4);
  int*      rowptr = (int*)alloc((size_t)(N + 1) * 4);
  int*      cursor = (int*)alloc((size_t)N * 4);
  int*      csr_src= (int*)alloc((size_t)E * 4);
  float*    csr_w  = (float*)alloc((size_t)E * 4);
  int*      bsum   = (int*)alloc(4096);

  // FLOAT32 output layout (elements): log0|log1|log2|soft0|soft1|soft2
  float* out = (float*)d_out;
  float* outlog[3]  = {out, out + 2 * (size_t)N, out + 8 * (size_t)N};
  float* outsoft[3] = {out + 29 * (size_t)N, out + 31 * (size_t)N, out + 37 * (size_t)N};

  if (used > ws_size) {
    k_zero_f<<<(out_size + 255) / 256, 256, 0, stream>>>(out, out_size);
    return;
  }

  float* w1f   = wbase + cd.off[0];
  float* b1f   = wbase + cd.off[1];
  float* ginw1 = wbase + cd.off[2];
  float* ginb1 = wbase + cd.off[3];
  float* ginw2 = wbase + cd.off[4];
  float* ginb2 = wbase + cd.off[5];
  float* wih   = wbase + cd.off[6];
  float* whh   = wbase + cd.off[7];
  float* bih   = wbase + cd.off[8];
  float* bhh   = wbase + cd.off[9];
  float* hw1   = wbase + cd.off[10];
  float* hb1   = wbase + cd.off[11];
  float* hw2_0 = wbase + cd.off[12];
  float* hb2_0 = wbase + cd.off[13];
  float* hw2_1 = wbase + cd.off[14];
  float* hb2_1 = wbase + cd.off[15];
  float* hw2_2 = wbase + cd.off[16];
  float* hb2_2 = wbase + cd.off[17];

  const int* dst = (const int*)d_in[1];       // edge_index[0]
  const int* src = (const int*)d_in[1] + E;   // edge_index[1]

  // ---- dtype probe + conversions ----
  k_detect<<<1, 64, 0, stream>>>((const uint32_t*)d_in[0], flag);
  k_cvtw<<<(wtotal + 255) / 256, 256, 0, stream>>>(cd, wbase, flag, wtotal);
  k_cvt_feat<<<((size_t)N * 128 + 255) / 256, 256, 0, stream>>>(d_in[0], aggb,
                                                                N * 128, flag);

  // ---- CSR build ----
  k_zero_i<<<(N + 255) / 256, 256, 0, stream>>>(deg, N);
  k_hist<<<(E + 255) / 256, 256, 0, stream>>>(dst, deg, E);
  int nb = (N + 1023) / 1024;
  k_scan1<<<nb, 256, 0, stream>>>(deg, bsum, N);
  k_scan2<<<1, 64, 0, stream>>>(bsum, nb, rowptr, N);
  k_scan3<<<nb, 256, 0, stream>>>(deg, bsum, rowptr, cursor, N);
  k_scatter<<<(E + 255) / 256, 256, 0, stream>>>(dst, src, d_in[2], cursor,
                                                 csr_src, csr_w, flag, E);

  int mmb = (N + 7) / 8;
  int hdb = (N + 255) / 256;

  // mlp1
  k_mms<1><<<mmb, 256, 0, stream>>>(aggb, w1f, b1f, xb, N);

  for (int i = 0; i < 3; i++) {
    k_spmm<<<(N + 1) / 2, 256, 0, stream>>>(xb, rowptr, csr_src, csr_w, aggb, N);
    k_grus<<<mmb, 256, 0, stream>>>(aggb, xb, wih + (size_t)i * 384 * 128,
                                    whh + (size_t)i * 384 * 128,
                                    bih + i * 384, bhh + i * 384, hb, N);
    k_mms<1><<<mmb, 256, 0, stream>>>(hb, ginw1 + (size_t)i * 128 * 128,
                                      ginb1 + i * 128, aggb, N);
    k_mms<2><<<mmb, 256, 0, stream>>>(aggb, ginw2 + (size_t)i * 128 * 128,
                                      ginb2 + i * 128, xb, N);
    k_mms<1><<<mmb, 256, 0, stream>>>(xb, hw1 + (size_t)i * 128 * 128,
                                      hb1 + i * 128, aggb, N);
    if (i == 0)
      k_heads<2><<<hdb, 256, 0, stream>>>(aggb, hw2_0, hb2_0, outlog[0], outsoft[0], N);
    else if (i == 1)
      k_heads<6><<<hdb, 256, 0, stream>>>(aggb, hw2_1, hb2_1, outlog[1], outsoft[1], N);
    else
      k_heads<21><<<hdb, 256, 0, stream>>>(aggb, hw2_2, hb2_2, outlog[2], outsoft[2], N);
  }
}

// Round 8
// 2719.268 us; speedup vs baseline: 7.4594x; 7.4594x over previous
//
#include <hip/hip_runtime.h>
#include <cstdint>
#include <cstddef>

// ---------------------------------------------------------------------------
// GatedGIN forward. Inputs bf16-or-f32 (runtime probe), OUTPUT = FLOAT32.
// fp32 compute, bf16 activation storage. Round 8: restore LDS-tiled k_mm
// (64x128 tile) and fused tiled k_gru (32x384, weights staged in LDS) --
// exonerated by Round-7 root cause (output dtype, not these kernels).
// Workspace ~94 MB.
// ---------------------------------------------------------------------------

static __device__ __forceinline__ float bf2f(uint16_t u) {
  return __uint_as_float(((uint32_t)u) << 16);
}
static __device__ __forceinline__ uint16_t f2b(float f) {
  uint32_t x = __float_as_uint(f);
  return (uint16_t)((x + 0x7FFFu + ((x >> 16) & 1u)) >> 16);
}
static __device__ __forceinline__ float sigmoidf_(float v) {
  return 1.f / (1.f + __expf(-v));
}

// ---------------- dtype probe ----------------
__global__ void k_detect(const uint32_t* __restrict__ u, int* __restrict__ flag) {
  int lane = threadIdx.x;  // 64 threads
  uint32_t low = u[lane] & 0xFFFFu;
  uint32_t e = (low >> 7) & 0xFFu;
  bool pass = (e == 0) || (e >= 110 && e <= 141);
  unsigned long long b = __ballot(pass);
  if (lane == 0) *flag = (__popcll(b) >= 32) ? 1 : 0;
}

// ---------------- upcast weights to f32 workspace ----------------
struct CvtDesc {
  const void* src[18];
  int off[19];
};

__global__ void k_cvtw(CvtDesc c, float* __restrict__ wbase,
                       const int* __restrict__ flag, int total) {
  int gid = blockIdx.x * 256 + threadIdx.x;
  if (gid >= total) return;
  int t = 0;
#pragma unroll
  for (int i = 1; i < 18; i++)
    if (gid >= c.off[i]) t = i;
  int local = gid - c.off[t];
  float v;
  if (*flag) v = bf2f(((const uint16_t*)c.src[t])[local]);
  else       v = ((const float*)c.src[t])[local];
  wbase[gid] = v;
}

__global__ void k_cvt_feat(const void* __restrict__ src, uint16_t* __restrict__ dst,
                           int n, const int* __restrict__ flag) {
  int i = blockIdx.x * 256 + threadIdx.x;
  if (i >= n) return;
  if (*flag) dst[i] = ((const uint16_t*)src)[i];
  else       dst[i] = f2b(((const float*)src)[i]);
}

__global__ void k_zero_i(int* __restrict__ p, int n) {
  int i = blockIdx.x * 256 + threadIdx.x;
  if (i < n) p[i] = 0;
}

__global__ void k_zero_f(float* __restrict__ p, int n) {
  int i = blockIdx.x * 256 + threadIdx.x;
  if (i < n) p[i] = 0.f;
}

// ---------------- CSR build ----------------
__global__ void k_hist(const int* __restrict__ dst, int* __restrict__ deg, int E) {
  int e = blockIdx.x * 256 + threadIdx.x;
  if (e < E) atomicAdd(&deg[dst[e]], 1);
}

__global__ void k_scan1(const int* __restrict__ deg, int* __restrict__ bsum, int n) {
  __shared__ int red[256];
  int t = threadIdx.x;
  int base = blockIdx.x * 1024;
  int s = 0;
#pragma unroll
  for (int i = 0; i < 4; i++) {
    int idx = base + i * 256 + t;
    if (idx < n) s += deg[idx];
  }
  red[t] = s;
  __syncthreads();
  for (int off = 128; off > 0; off >>= 1) {
    if (t < off) red[t] += red[t + off];
    __syncthreads();
  }
  if (t == 0) bsum[blockIdx.x] = red[0];
}

__global__ void k_scan2(int* bsum, int nb, int* rowptr, int n) {
  if (threadIdx.x == 0 && blockIdx.x == 0) {
    int run = 0;
    for (int b = 0; b < nb; b++) {
      int v = bsum[b];
      bsum[b] = run;
      run += v;
    }
    rowptr[n] = run;  // == E
  }
}

__global__ void k_scan3(const int* __restrict__ deg, const int* __restrict__ bsum,
                        int* __restrict__ rowptr, int* __restrict__ cursor, int n) {
  __shared__ int lds[256];
  int t = threadIdx.x;
  int base = blockIdx.x * 1024 + t * 4;
  int v0 = 0, v1 = 0, v2 = 0, v3 = 0;
  if (base + 0 < n) v0 = deg[base + 0];
  if (base + 1 < n) v1 = deg[base + 1];
  if (base + 2 < n) v2 = deg[base + 2];
  if (base + 3 < n) v3 = deg[base + 3];
  int s = v0 + v1 + v2 + v3;
  lds[t] = s;
  __syncthreads();
  for (int off = 1; off < 256; off <<= 1) {
    int u = (t >= off) ? lds[t - off] : 0;
    __syncthreads();
    lds[t] += u;
    __syncthreads();
  }
  int run = lds[t] - s + bsum[blockIdx.x];
  if (base + 0 < n) { rowptr[base + 0] = run; cursor[base + 0] = run; run += v0; }
  if (base + 1 < n) { rowptr[base + 1] = run; cursor[base + 1] = run; run += v1; }
  if (base + 2 < n) { rowptr[base + 2] = run; cursor[base + 2] = run; run += v2; }
  if (base + 3 < n) { rowptr[base + 3] = run; cursor[base + 3] = run; run += v3; }
}

__global__ void k_scatter(const int* __restrict__ dst, const int* __restrict__ src,
                          const void* __restrict__ w, int* __restrict__ cursor,
                          int* __restrict__ csr_src, float* __restrict__ csr_w,
                          const int* __restrict__ flag, int E) {
  int e = blockIdx.x * 256 + threadIdx.x;
  if (e < E) {
    int d = dst[e];
    int pos = atomicAdd(&cursor[d], 1);
    csr_src[pos] = src[e];
    float wv;
    if (*flag) wv = bf2f(((const uint16_t*)w)[e]);
    else       wv = ((const float*)w)[e];
    csr_w[pos] = wv;
  }
}

// ---------------- SpMM gather ----------------
__global__ void k_spmm(const uint16_t* __restrict__ x, const int* __restrict__ rowptr,
                       const int* __restrict__ csr_src, const float* __restrict__ csr_w,
                       uint16_t* __restrict__ agg, int n) {
  int node = blockIdx.x * 2 + (threadIdx.x >> 7);
  int f = threadIdx.x & 127;
  if (node >= n) return;
  int p0 = rowptr[node], p1 = rowptr[node + 1];
  float acc = 0.f;
  int p = p0;
  for (; p + 1 < p1; p += 2) {
    int s0 = csr_src[p], s1 = csr_src[p + 1];
    float w0 = csr_w[p], w1 = csr_w[p + 1];
    acc = fmaf(w0, bf2f(x[(size_t)s0 * 128 + f]), acc);
    acc = fmaf(w1, bf2f(x[(size_t)s1 * 128 + f]), acc);
  }
  if (p < p1) acc = fmaf(csr_w[p], bf2f(x[(size_t)csr_src[p] * 128 + f]), acc);
  agg[(size_t)node * 128 + f] = f2b(acc);
}

// ---------------- tiled matmul: C = act(A[N,128]bf16 @ W[128,128]f32^T + b) -
// EPI 1 = relu; EPI 2 = relu + row-norm x/sqrt(1+sum x^2). Out bf16.
// Block 256 thr, tile 64 rows x 128 cols, micro 4x8, K=128 in two 64-halves.
template <int EPI>
__launch_bounds__(256)
__global__ void k_mm(const uint16_t* __restrict__ A, const float* __restrict__ W,
                     const float* __restrict__ bias, uint16_t* __restrict__ C,
                     int nrows) {
  __shared__ float aT[64][68];   // [k][row]
  __shared__ float wT[64][132];  // [k][col]
  int tid = threadIdx.x;
  int tx = tid & 15, ty = tid >> 4;
  int r0 = blockIdx.x * 64;

  float acc[4][8];
#pragma unroll
  for (int i = 0; i < 4; i++)
#pragma unroll
    for (int j = 0; j < 8; j++) acc[i][j] = 0.f;

  for (int kh = 0; kh < 2; ++kh) {
    int kb = kh * 64;
#pragma unroll
    for (int i = 0; i < 16; i++) {
      int q = i * 256 + tid;
      int row = q >> 6, k = q & 63;
      int gr = r0 + row;
      aT[k][row] = (gr < nrows) ? bf2f(A[(size_t)gr * 128 + kb + k]) : 0.f;
    }
#pragma unroll
    for (int i = 0; i < 32; i++) {
      int q = i * 256 + tid;
      int c = q >> 6, k = q & 63;
      wT[k][c] = W[(size_t)c * 128 + kb + k];
    }
    __syncthreads();
#pragma unroll 4
    for (int k = 0; k < 64; k++) {
      float4 av = *reinterpret_cast<const float4*>(&aT[k][ty * 4]);
      float4 wv0 = *reinterpret_cast<const float4*>(&wT[k][tx * 4]);
      float4 wv1 = *reinterpret_cast<const float4*>(&wT[k][64 + tx * 4]);
      float ar[4] = {av.x, av.y, av.z, av.w};
      float wr[8] = {wv0.x, wv0.y, wv0.z, wv0.w, wv1.x, wv1.y, wv1.z, wv1.w};
#pragma unroll
      for (int i = 0; i < 4; i++)
#pragma unroll
        for (int j = 0; j < 8; j++) acc[i][j] = fmaf(ar[i], wr[j], acc[i][j]);
    }
    __syncthreads();
  }

  float v[4][8];
#pragma unroll
  for (int i = 0; i < 4; i++) {
#pragma unroll
    for (int j = 0; j < 8; j++) {
      int cl = (j < 4) ? (tx * 4 + j) : (64 + tx * 4 + (j - 4));
      v[i][j] = fmaxf(acc[i][j] + bias[cl], 0.f);
    }
  }

  if (EPI == 2) {
    float* rs = &wT[0][0];  // safe: all compute done, last barrier passed
#pragma unroll
    for (int i = 0; i < 4; i++) {
      float s = 0.f;
#pragma unroll
      for (int j = 0; j < 8; j++) s = fmaf(v[i][j], v[i][j], s);
      rs[(ty * 4 + i) * 17 + tx] = s;
    }
    __syncthreads();
#pragma unroll
    for (int i = 0; i < 4; i++) {
      float s = 0.f;
      for (int t2 = 0; t2 < 16; t2++) s += rs[(ty * 4 + i) * 17 + t2];
      float sc = rsqrtf(1.f + s);
#pragma unroll
      for (int j = 0; j < 8; j++) v[i][j] *= sc;
    }
  }

#pragma unroll
  for (int i = 0; i < 4; i++) {
    int r = r0 + ty * 4 + i;
    if (r >= nrows) continue;
#pragma unroll
    for (int j = 0; j < 8; j++) {
      int cl = (j < 4) ? (tx * 4 + j) : (64 + tx * 4 + (j - 4));
      C[(size_t)r * 128 + cl] = f2b(v[i][j]);
    }
  }
}

// ---------------- fused tiled GRU ----------------
// One block: 32 rows x all 128 h-cols. Accumulates 6 sub-tiles:
//   gi = agg @ wih^T (ir|iz|inn), gh = x @ whh^T (hr|hz|hn), K=128 in 16-chunks
// staged through LDS (weights + A/x rows). Gates thread-local in epilogue.
__launch_bounds__(256)
__global__ void k_gru(const uint16_t* __restrict__ aggb, const uint16_t* __restrict__ xb,
                      const float* __restrict__ wih, const float* __restrict__ whh,
                      const float* __restrict__ bih, const float* __restrict__ bhh,
                      uint16_t* __restrict__ hb, int n) {
  __shared__ float wi[16][388];  // [k][out 0..384)
  __shared__ float wh[16][388];
  __shared__ float at[16][36];   // [k][row]  (agg)
  __shared__ float xt[16][36];   // [k][row]  (x)

  int tid = threadIdx.x;
  int cg = tid & 31;   // col group: cols cg*4 .. +3  (of 128)
  int rg = tid >> 5;   // row group: rows rg*4 .. +3  (of 32)
  int r0 = blockIdx.x * 32;

  float accA[3][4][4];  // ir, iz, inn
  float accB[3][4][4];  // hr, hz, hn
#pragma unroll
  for (int g = 0; g < 3; g++)
#pragma unroll
    for (int r = 0; r < 4; r++)
#pragma unroll
      for (int c = 0; c < 4; c++) { accA[g][r][c] = 0.f; accB[g][r][c] = 0.f; }

  for (int kb = 0; kb < 128; kb += 16) {
    // stage W chunks: 384 out x 16 k, float4 over k
#pragma unroll
    for (int i = 0; i < 6; i++) {
      int q = i * 256 + tid;       // < 1536
      int c = q >> 2;              // 0..383
      int k4 = (q & 3) * 4;        // 0,4,8,12
      float4 v = *reinterpret_cast<const float4*>(&wih[(size_t)c * 128 + kb + k4]);
      wi[k4 + 0][c] = v.x; wi[k4 + 1][c] = v.y; wi[k4 + 2][c] = v.z; wi[k4 + 3][c] = v.w;
      float4 u = *reinterpret_cast<const float4*>(&whh[(size_t)c * 128 + kb + k4]);
      wh[k4 + 0][c] = u.x; wh[k4 + 1][c] = u.y; wh[k4 + 2][c] = u.z; wh[k4 + 3][c] = u.w;
    }
    // stage A/x chunks: 32 rows x 16 k (bf16 -> f32)
#pragma unroll
    for (int i = 0; i < 2; i++) {
      int q = i * 256 + tid;       // < 512
      int row = q >> 4, k = q & 15;
      int gr = r0 + row;
      at[k][row] = (gr < n) ? bf2f(aggb[(size_t)gr * 128 + kb + k]) : 0.f;
      xt[k][row] = (gr < n) ? bf2f(xb[(size_t)gr * 128 + kb + k]) : 0.f;
    }
    __syncthreads();
#pragma unroll 2
    for (int k = 0; k < 16; k++) {
      float4 aa = *reinterpret_cast<const float4*>(&at[k][rg * 4]);
      float4 ax = *reinterpret_cast<const float4*>(&xt[k][rg * 4]);
      float4 i0 = *reinterpret_cast<const float4*>(&wi[k][cg * 4]);
      float4 i1 = *reinterpret_cast<const float4*>(&wi[k][128 + cg * 4]);
      float4 i2 = *reinterpret_cast<const float4*>(&wi[k][256 + cg * 4]);
      float4 h0 = *reinterpret_cast<const float4*>(&wh[k][cg * 4]);
      float4 h1 = *reinterpret_cast<const float4*>(&wh[k][128 + cg * 4]);
      float4 h2 = *reinterpret_cast<const float4*>(&wh[k][256 + cg * 4]);
      float av[4] = {aa.x, aa.y, aa.z, aa.w};
      float xv[4] = {ax.x, ax.y, ax.z, ax.w};
      float wiv[12] = {i0.x, i0.y, i0.z, i0.w, i1.x, i1.y, i1.z, i1.w,
                       i2.x, i2.y, i2.z, i2.w};
      float whv[12] = {h0.x, h0.y, h0.z, h0.w, h1.x, h1.y, h1.z, h1.w,
                       h2.x, h2.y, h2.z, h2.w};
#pragma unroll
      for (int r = 0; r < 4; r++)
#pragma unroll
        for (int c = 0; c < 4; c++) {
          accA[0][r][c] = fmaf(av[r], wiv[c],     accA[0][r][c]);
          accA[1][r][c] = fmaf(av[r], wiv[4 + c], accA[1][r][c]);
          accA[2][r][c] = fmaf(av[r], wiv[8 + c], accA[2][r][c]);
          accB[0][r][c] = fmaf(xv[r], whv[c],     accB[0][r][c]);
          accB[1][r][c] = fmaf(xv[r], whv[4 + c], accB[1][r][c]);
          accB[2][r][c] = fmaf(xv[r], whv[8 + c], accB[2][r][c]);
        }
    }
    __syncthreads();
  }

  // gates epilogue (thread-local)
#pragma unroll
  for (int r = 0; r < 4; r++) {
    int row = r0 + rg * 4 + r;
    if (row >= n) continue;
#pragma unroll
    for (int c = 0; c < 4; c++) {
      int col = cg * 4 + c;
      float ir = accA[0][r][c] + bih[col];
      float iz = accA[1][r][c] + bih[128 + col];
      float in_ = accA[2][r][c] + bih[256 + col];
      float hr = accB[0][r][c] + bhh[col];
      float hz = accB[1][r][c] + bhh[128 + col];
      float hn = accB[2][r][c] + bhh[256 + col];
      float rr = sigmoidf_(ir + hr);
      float zz = sigmoidf_(iz + hz);
      float nn = tanhf(fmaf(rr, hn, in_));
      float xval = bf2f(xb[(size_t)row * 128 + col]);
      hb[(size_t)row * 128 + col] = f2b(fmaf(zz, xval - nn, nn));
    }
  }
}

// ---------------- head: one thread per node, FLOAT32 output ----------------
template <int C>
__global__ void k_heads(const uint16_t* __restrict__ hh, const float* __restrict__ w2,
                        const float* __restrict__ b2,
                        float* __restrict__ out_log, float* __restrict__ out_soft,
                        int n) {
  int node = blockIdx.x * 256 + threadIdx.x;
  if (node >= n) return;
  const uint16_t* row = hh + (size_t)node * 128;
  float lg[C];
#pragma unroll
  for (int c = 0; c < C; c++) lg[c] = b2[c];
  for (int k = 0; k < 128; k++) {
    float xv = bf2f(row[k]);
#pragma unroll
    for (int c = 0; c < C; c++) lg[c] = fmaf(xv, w2[c * 128 + k], lg[c]);
  }
  float m = lg[0];
#pragma unroll
  for (int c = 1; c < C; c++) m = fmaxf(m, lg[c]);
  float s = 0.f;
  float e[C];
#pragma unroll
  for (int c = 0; c < C; c++) { e[c] = __expf(lg[c] - m); s += e[c]; }
  float ls = __logf(s);
  float inv = 1.f / s;
#pragma unroll
  for (int c = 0; c < C; c++) {
    out_log[(size_t)node * C + c] = lg[c] - m - ls;
    out_soft[(size_t)node * C + c] = e[c] * inv;
  }
}

// ---------------------------------------------------------------------------
extern "C" void kernel_launch(void* const* d_in, const int* in_sizes, int n_in,
                              void* d_out, int out_size, void* d_ws, size_t ws_size,
                              hipStream_t stream) {
  const int N = in_sizes[0] / 128;   // 100000
  const int E = in_sizes[2];         // 1600000

  static const int wn[18] = {16384, 128, 49152, 384, 49152, 384,
                             147456, 147456, 1152, 1152, 49152, 384,
                             256, 2, 768, 6, 2688, 21};
  CvtDesc cd;
  int off = 0;
  for (int i = 0; i < 18; i++) {
    cd.src[i] = d_in[3 + i];
    cd.off[i] = off;
    off += wn[i];
  }
  cd.off[18] = off;
  const int wtotal = off;  // 466077

  // ---- workspace bump allocator (~94 MB) ----
  char* p = (char*)d_ws;
  size_t used = 0;
  auto alloc = [&](size_t bytes) -> char* {
    char* r = p;
    size_t b = (bytes + 255) & ~(size_t)255;
    p += b;
    used += b;
    return r;
  };
  int*      flag   = (int*)alloc(256);
  float*    wbase  = (float*)alloc((size_t)wtotal * 4);
  uint16_t* xb     = (uint16_t*)alloc((size_t)N * 128 * 2);
  uint16_t* aggb   = (uint16_t*)alloc((size_t)N * 128 * 2);
  uint16_t* hb     = (uint16_t*)alloc((size_t)N * 128 * 2);
  int*      deg    = (int*)alloc((size_t)N * 4);
  int*      rowptr = (int*)alloc((size_t)(N + 1) * 4);
  int*      cursor = (int*)alloc((size_t)N * 4);
  int*      csr_src= (int*)alloc((size_t)E * 4);
  float*    csr_w  = (float*)alloc((size_t)E * 4);
  int*      bsum   = (int*)alloc(4096);

  // FLOAT32 output layout (elements): log0|log1|log2|soft0|soft1|soft2
  float* out = (float*)d_out;
  float* outlog[3]  = {out, out + 2 * (size_t)N, out + 8 * (size_t)N};
  float* outsoft[3] = {out + 29 * (size_t)N, out + 31 * (size_t)N, out + 37 * (size_t)N};

  if (used > ws_size) {
    k_zero_f<<<(out_size + 255) / 256, 256, 0, stream>>>(out, out_size);
    return;
  }

  float* w1f   = wbase + cd.off[0];
  float* b1f   = wbase + cd.off[1];
  float* ginw1 = wbase + cd.off[2];
  float* ginb1 = wbase + cd.off[3];
  float* ginw2 = wbase + cd.off[4];
  float* ginb2 = wbase + cd.off[5];
  float* wih   = wbase + cd.off[6];
  float* whh   = wbase + cd.off[7];
  float* bih   = wbase + cd.off[8];
  float* bhh   = wbase + cd.off[9];
  float* hw1   = wbase + cd.off[10];
  float* hb1   = wbase + cd.off[11];
  float* hw2_0 = wbase + cd.off[12];
  float* hb2_0 = wbase + cd.off[13];
  float* hw2_1 = wbase + cd.off[14];
  float* hb2_1 = wbase + cd.off[15];
  float* hw2_2 = wbase + cd.off[16];
  float* hb2_2 = wbase + cd.off[17];

  const int* dst = (const int*)d_in[1];       // edge_index[0]
  const int* src = (const int*)d_in[1] + E;   // edge_index[1]

  // ---- dtype probe + conversions ----
  k_detect<<<1, 64, 0, stream>>>((const uint32_t*)d_in[0], flag);
  k_cvtw<<<(wtotal + 255) / 256, 256, 0, stream>>>(cd, wbase, flag, wtotal);
  k_cvt_feat<<<((size_t)N * 128 + 255) / 256, 256, 0, stream>>>(d_in[0], aggb,
                                                                N * 128, flag);

  // ---- CSR build ----
  k_zero_i<<<(N + 255) / 256, 256, 0, stream>>>(deg, N);
  k_hist<<<(E + 255) / 256, 256, 0, stream>>>(dst, deg, E);
  int nb = (N + 1023) / 1024;
  k_scan1<<<nb, 256, 0, stream>>>(deg, bsum, N);
  k_scan2<<<1, 64, 0, stream>>>(bsum, nb, rowptr, N);
  k_scan3<<<nb, 256, 0, stream>>>(deg, bsum, rowptr, cursor, N);
  k_scatter<<<(E + 255) / 256, 256, 0, stream>>>(dst, src, d_in[2], cursor,
                                                 csr_src, csr_w, flag, E);

  int mmrb = (N + 63) / 64;   // 1563
  int grub = (N + 31) / 32;   // 3125
  int hdb  = (N + 255) / 256;

  // mlp1: xb = relu(features(aggb) @ w1^T + b1)
  k_mm<1><<<mmrb, 256, 0, stream>>>(aggb, w1f, b1f, xb, N);

  for (int i = 0; i < 3; i++) {
    k_spmm<<<(N + 1) / 2, 256, 0, stream>>>(xb, rowptr, csr_src, csr_w, aggb, N);
    k_gru<<<grub, 256, 0, stream>>>(aggb, xb, wih + (size_t)i * 384 * 128,
                                    whh + (size_t)i * 384 * 128,
                                    bih + i * 384, bhh + i * 384, hb, N);
    k_mm<1><<<mmrb, 256, 0, stream>>>(hb, ginw1 + (size_t)i * 128 * 128,
                                      ginb1 + i * 128, aggb, N);
    k_mm<2><<<mmrb, 256, 0, stream>>>(aggb, ginw2 + (size_t)i * 128 * 128,
                                      ginb2 + i * 128, xb, N);
    k_mm<1><<<mmrb, 256, 0, stream>>>(xb, hw1 + (size_t)i * 128 * 128,
                                      hb1 + i * 128, aggb, N);
    if (i == 0)
      k_heads<2><<<hdb, 256, 0, stream>>>(aggb, hw2_0, hb2_0, outlog[0], outsoft[0], N);
    else if (i == 1)
      k_heads<6><<<hdb, 256, 0, stream>>>(aggb, hw2_1, hb2_1, outlog[1], outsoft[1], N);
    else
      k_heads<21><<<hdb, 256, 0, stream>>>(aggb, hw2_2, hb2_2, outlog[2], outsoft[2], N);
  }
}

// Round 9
// 1526.238 us; speedup vs baseline: 13.2902x; 1.7817x over previous
//
#include <hip/hip_runtime.h>
#include <cstdint>
#include <cstddef>

// ---------------------------------------------------------------------------
// GatedGIN forward. Inputs bf16-or-f32 (runtime probe), OUTPUT = FLOAT32.
// Round 9: all dense matmuls on bf16 MFMA (16x16x32), fragments loaded
// DIRECTLY from row-major global (A[m][k] and W[n][k] are both 8-contiguous
// bf16 = one 16B load) -- zero LDS, zero barriers in the hot kernels.
// GRU gates fused in-register (gi/gh tiles share lane/reg layout).
// f32 accumulate; weights bf16 (lossless: inputs are bf16).
// ---------------------------------------------------------------------------

typedef short  v8s __attribute__((ext_vector_type(8)));
typedef float  v4f __attribute__((ext_vector_type(4)));

static __device__ __forceinline__ float bf2f(uint16_t u) {
  return __uint_as_float(((uint32_t)u) << 16);
}
static __device__ __forceinline__ uint16_t f2b(float f) {
  uint32_t x = __float_as_uint(f);
  return (uint16_t)((x + 0x7FFFu + ((x >> 16) & 1u)) >> 16);
}
static __device__ __forceinline__ float sigmoidf_(float v) {
  return 1.f / (1.f + __expf(-v));
}

// ---------------- dtype probe ----------------
__global__ void k_detect(const uint32_t* __restrict__ u, int* __restrict__ flag) {
  int lane = threadIdx.x;  // 64 threads
  uint32_t low = u[lane] & 0xFFFFu;
  uint32_t e = (low >> 7) & 0xFFu;
  bool pass = (e == 0) || (e >= 110 && e <= 141);
  unsigned long long b = __ballot(pass);
  if (lane == 0) *flag = (__popcll(b) >= 32) ? 1 : 0;
}

// ---------------- upcast weights to f32 workspace ----------------
struct CvtDesc {
  const void* src[18];
  int off[19];
};

__global__ void k_cvtw(CvtDesc c, float* __restrict__ wbase,
                       const int* __restrict__ flag, int total) {
  int gid = blockIdx.x * 256 + threadIdx.x;
  if (gid >= total) return;
  int t = 0;
#pragma unroll
  for (int i = 1; i < 18; i++)
    if (gid >= c.off[i]) t = i;
  int local = gid - c.off[t];
  float v;
  if (*flag) v = bf2f(((const uint16_t*)c.src[t])[local]);
  else       v = ((const float*)c.src[t])[local];
  wbase[gid] = v;
}

// f32 -> bf16 mirror of the weight arena (for MFMA operands)
__global__ void k_cvtb(const float* __restrict__ src, uint16_t* __restrict__ dst,
                       int n) {
  int i = blockIdx.x * 256 + threadIdx.x;
  if (i < n) dst[i] = f2b(src[i]);
}

__global__ void k_cvt_feat(const void* __restrict__ src, uint16_t* __restrict__ dst,
                           int n, const int* __restrict__ flag) {
  int i = blockIdx.x * 256 + threadIdx.x;
  if (i >= n) return;
  if (*flag) dst[i] = ((const uint16_t*)src)[i];
  else       dst[i] = f2b(((const float*)src)[i]);
}

__global__ void k_zero_i(int* __restrict__ p, int n) {
  int i = blockIdx.x * 256 + threadIdx.x;
  if (i < n) p[i] = 0;
}

__global__ void k_zero_f(float* __restrict__ p, int n) {
  int i = blockIdx.x * 256 + threadIdx.x;
  if (i < n) p[i] = 0.f;
}

// ---------------- CSR build ----------------
__global__ void k_hist(const int* __restrict__ dst, int* __restrict__ deg, int E) {
  int e = blockIdx.x * 256 + threadIdx.x;
  if (e < E) atomicAdd(&deg[dst[e]], 1);
}

__global__ void k_scan1(const int* __restrict__ deg, int* __restrict__ bsum, int n) {
  __shared__ int red[256];
  int t = threadIdx.x;
  int base = blockIdx.x * 1024;
  int s = 0;
#pragma unroll
  for (int i = 0; i < 4; i++) {
    int idx = base + i * 256 + t;
    if (idx < n) s += deg[idx];
  }
  red[t] = s;
  __syncthreads();
  for (int off = 128; off > 0; off >>= 1) {
    if (t < off) red[t] += red[t + off];
    __syncthreads();
  }
  if (t == 0) bsum[blockIdx.x] = red[0];
}

__global__ void k_scan2(int* bsum, int nb, int* rowptr, int n) {
  if (threadIdx.x == 0 && blockIdx.x == 0) {
    int run = 0;
    for (int b = 0; b < nb; b++) {
      int v = bsum[b];
      bsum[b] = run;
      run += v;
    }
    rowptr[n] = run;  // == E
  }
}

__global__ void k_scan3(const int* __restrict__ deg, const int* __restrict__ bsum,
                        int* __restrict__ rowptr, int* __restrict__ cursor, int n) {
  __shared__ int lds[256];
  int t = threadIdx.x;
  int base = blockIdx.x * 1024 + t * 4;
  int v0 = 0, v1 = 0, v2 = 0, v3 = 0;
  if (base + 0 < n) v0 = deg[base + 0];
  if (base + 1 < n) v1 = deg[base + 1];
  if (base + 2 < n) v2 = deg[base + 2];
  if (base + 3 < n) v3 = deg[base + 3];
  int s = v0 + v1 + v2 + v3;
  lds[t] = s;
  __syncthreads();
  for (int off = 1; off < 256; off <<= 1) {
    int u = (t >= off) ? lds[t - off] : 0;
    __syncthreads();
    lds[t] += u;
    __syncthreads();
  }
  int run = lds[t] - s + bsum[blockIdx.x];
  if (base + 0 < n) { rowptr[base + 0] = run; cursor[base + 0] = run; run += v0; }
  if (base + 1 < n) { rowptr[base + 1] = run; cursor[base + 1] = run; run += v1; }
  if (base + 2 < n) { rowptr[base + 2] = run; cursor[base + 2] = run; run += v2; }
  if (base + 3 < n) { rowptr[base + 3] = run; cursor[base + 3] = run; run += v3; }
}

__global__ void k_scatter(const int* __restrict__ dst, const int* __restrict__ src,
                          const void* __restrict__ w, int* __restrict__ cursor,
                          int* __restrict__ csr_src, float* __restrict__ csr_w,
                          const int* __restrict__ flag, int E) {
  int e = blockIdx.x * 256 + threadIdx.x;
  if (e < E) {
    int d = dst[e];
    int pos = atomicAdd(&cursor[d], 1);
    csr_src[pos] = src[e];
    float wv;
    if (*flag) wv = bf2f(((const uint16_t*)w)[e]);
    else       wv = ((const float*)w)[e];
    csr_w[pos] = wv;
  }
}

// ---------------- SpMM gather: 4 nodes/block, 64 thr/node, ushort2/lane ----
__global__ void k_spmm(const uint16_t* __restrict__ x, const int* __restrict__ rowptr,
                       const int* __restrict__ csr_src, const float* __restrict__ csr_w,
                       uint16_t* __restrict__ agg, int n) {
  int node = blockIdx.x * 4 + (threadIdx.x >> 6);
  int lane = threadIdx.x & 63;
  if (node >= n) return;
  int p0 = rowptr[node], p1 = rowptr[node + 1];
  float a0 = 0.f, a1 = 0.f;
  int p = p0;
  for (; p + 1 < p1; p += 2) {
    int s0 = csr_src[p], s1 = csr_src[p + 1];
    float w0 = csr_w[p], w1 = csr_w[p + 1];
    uint32_t u0 = *reinterpret_cast<const uint32_t*>(x + (size_t)s0 * 128 + lane * 2);
    uint32_t u1 = *reinterpret_cast<const uint32_t*>(x + (size_t)s1 * 128 + lane * 2);
    a0 = fmaf(w0, bf2f((uint16_t)u0), a0);
    a1 = fmaf(w0, bf2f((uint16_t)(u0 >> 16)), a1);
    a0 = fmaf(w1, bf2f((uint16_t)u1), a0);
    a1 = fmaf(w1, bf2f((uint16_t)(u1 >> 16)), a1);
  }
  if (p < p1) {
    float w0 = csr_w[p];
    uint32_t u0 = *reinterpret_cast<const uint32_t*>(x + (size_t)csr_src[p] * 128 + lane * 2);
    a0 = fmaf(w0, bf2f((uint16_t)u0), a0);
    a1 = fmaf(w0, bf2f((uint16_t)(u0 >> 16)), a1);
  }
  uint32_t packed = (uint32_t)f2b(a0) | ((uint32_t)f2b(a1) << 16);
  *reinterpret_cast<uint32_t*>(agg + (size_t)node * 128 + lane * 2) = packed;
}

// ---------------- MFMA matmul: C = act(A[N,128]bf16 @ W[128,128]bf16^T + b) -
// EPI 1 = relu; EPI 2 = relu + row-norm x/sqrt(1+sum x^2). Out bf16.
// 4 waves/block, each wave: 16 rows x 128 cols (8 n-tiles), K=128 (4 chunks).
// Fragments loaded directly from global; no LDS.
template <int EPI>
__launch_bounds__(256)
__global__ void k_mm(const uint16_t* __restrict__ A, const uint16_t* __restrict__ W,
                     const float* __restrict__ bias, uint16_t* __restrict__ C,
                     int nrows) {
  int wave = threadIdx.x >> 6, lane = threadIdx.x & 63;
  int n0 = lane & 15, quad = lane >> 4;
  int m16 = (blockIdx.x * 4 + wave) * 16;
  int arow = m16 + n0;
  bool aok = arow < nrows;
  const v8s z8 = {0, 0, 0, 0, 0, 0, 0, 0};

  v4f acc[8];
#pragma unroll
  for (int t = 0; t < 8; t++) acc[t] = {0.f, 0.f, 0.f, 0.f};

  const uint16_t* ap = A + (size_t)arow * 128 + quad * 8;
#pragma unroll
  for (int kc = 0; kc < 4; kc++) {
    v8s af = aok ? *reinterpret_cast<const v8s*>(ap + kc * 32) : z8;
#pragma unroll
    for (int t = 0; t < 8; t++) {
      v8s bf = *reinterpret_cast<const v8s*>(W + (size_t)(t * 16 + n0) * 128 + kc * 32 + quad * 8);
      acc[t] = __builtin_amdgcn_mfma_f32_16x16x32_bf16(af, bf, acc[t], 0, 0, 0);
    }
  }

  // lane holds D[row = m16 + quad*4 + r][col = 16t + n0] = acc[t][r]
  float vv[8][4];
#pragma unroll
  for (int t = 0; t < 8; t++) {
    float b = bias[t * 16 + n0];
#pragma unroll
    for (int r = 0; r < 4; r++) vv[t][r] = fmaxf(acc[t][r] + b, 0.f);
  }

  if (EPI == 2) {
#pragma unroll
    for (int r = 0; r < 4; r++) {
      float ss = 0.f;
#pragma unroll
      for (int t = 0; t < 8; t++) ss = fmaf(vv[t][r], vv[t][r], ss);
      // reduce over the 16 lanes of this quad (rows match within a quad)
      ss += __shfl_xor(ss, 1);
      ss += __shfl_xor(ss, 2);
      ss += __shfl_xor(ss, 4);
      ss += __shfl_xor(ss, 8);
      float sc = rsqrtf(1.f + ss);
#pragma unroll
      for (int t = 0; t < 8; t++) vv[t][r] *= sc;
    }
  }

#pragma unroll
  for (int r = 0; r < 4; r++) {
    int row = m16 + quad * 4 + r;
    if (row >= nrows) continue;
#pragma unroll
    for (int t = 0; t < 8; t++)
      C[(size_t)row * 128 + t * 16 + n0] = f2b(vv[t][r]);
  }
}

// ---------------- MFMA fused GRU ----------------
// Block 256 = 4 waves over the SAME 16 rows; wave w covers h-cols [32w,32w+32).
// Per h-col-tile: 3 wih tiles (r|z|n) + 3 whh tiles; gi/gh share (row,col)
// lane/reg layout -> gates fully in-register. No LDS.
__launch_bounds__(256)
__global__ void k_gru(const uint16_t* __restrict__ aggb, const uint16_t* __restrict__ xb,
                      const uint16_t* __restrict__ wih, const uint16_t* __restrict__ whh,
                      const float* __restrict__ bih, const float* __restrict__ bhh,
                      uint16_t* __restrict__ hb, int n) {
  int wave = threadIdx.x >> 6, lane = threadIdx.x & 63;
  int n0 = lane & 15, quad = lane >> 4;
  int m16 = blockIdx.x * 16;
  int arow = m16 + n0;
  bool aok = arow < n;
  const v8s z8 = {0, 0, 0, 0, 0, 0, 0, 0};

  v4f accI[2][3], accH[2][3];
#pragma unroll
  for (int u = 0; u < 2; u++)
#pragma unroll
    for (int g = 0; g < 3; g++) {
      accI[u][g] = {0.f, 0.f, 0.f, 0.f};
      accH[u][g] = {0.f, 0.f, 0.f, 0.f};
    }

  const uint16_t* ap = aggb + (size_t)arow * 128 + quad * 8;
  const uint16_t* xp = xb + (size_t)arow * 128 + quad * 8;
#pragma unroll
  for (int kc = 0; kc < 4; kc++) {
    v8s af = aok ? *reinterpret_cast<const v8s*>(ap + kc * 32) : z8;
    v8s xf = aok ? *reinterpret_cast<const v8s*>(xp + kc * 32) : z8;
#pragma unroll
    for (int u = 0; u < 2; u++) {
      int hc = wave * 32 + u * 16 + n0;  // h-col (== W row within gate block)
#pragma unroll
      for (int g = 0; g < 3; g++) {
        size_t woff = (size_t)(g * 128 + hc) * 128 + kc * 32 + quad * 8;
        v8s bi = *reinterpret_cast<const v8s*>(wih + woff);
        accI[u][g] = __builtin_amdgcn_mfma_f32_16x16x32_bf16(af, bi, accI[u][g], 0, 0, 0);
        v8s bh = *reinterpret_cast<const v8s*>(whh + woff);
        accH[u][g] = __builtin_amdgcn_mfma_f32_16x16x32_bf16(xf, bh, accH[u][g], 0, 0, 0);
      }
    }
  }

  // gates epilogue: lane holds rows m16+quad*4+r, col = wave*32 + u*16 + n0
#pragma unroll
  for (int u = 0; u < 2; u++) {
    int col = wave * 32 + u * 16 + n0;
    float bir = bih[col], biz = bih[128 + col], bin = bih[256 + col];
    float bhr = bhh[col], bhz = bhh[128 + col], bhn = bhh[256 + col];
#pragma unroll
    for (int r = 0; r < 4; r++) {
      int row = m16 + quad * 4 + r;
      if (row >= n) continue;
      float ir = accI[u][0][r] + bir;
      float iz = accI[u][1][r] + biz;
      float in_ = accI[u][2][r] + bin;
      float hr = accH[u][0][r] + bhr;
      float hz = accH[u][1][r] + bhz;
      float hn = accH[u][2][r] + bhn;
      float rr = sigmoidf_(ir + hr);
      float zz = sigmoidf_(iz + hz);
      float nn = tanhf(fmaf(rr, hn, in_));
      float xv = bf2f(xb[(size_t)row * 128 + col]);
      hb[(size_t)row * 128 + col] = f2b(fmaf(zz, xv - nn, nn));
    }
  }
}

// ---------------- head: one thread per node, FLOAT32 output ----------------
template <int C>
__global__ void k_heads(const uint16_t* __restrict__ hh, const float* __restrict__ w2,
                        const float* __restrict__ b2,
                        float* __restrict__ out_log, float* __restrict__ out_soft,
                        int n) {
  int node = blockIdx.x * 256 + threadIdx.x;
  if (node >= n) return;
  const uint16_t* row = hh + (size_t)node * 128;
  float lg[C];
#pragma unroll
  for (int c = 0; c < C; c++) lg[c] = b2[c];
  for (int k = 0; k < 128; k++) {
    float xv = bf2f(row[k]);
#pragma unroll
    for (int c = 0; c < C; c++) lg[c] = fmaf(xv, w2[c * 128 + k], lg[c]);
  }
  float m = lg[0];
#pragma unroll
  for (int c = 1; c < C; c++) m = fmaxf(m, lg[c]);
  float s = 0.f;
  float e[C];
#pragma unroll
  for (int c = 0; c < C; c++) { e[c] = __expf(lg[c] - m); s += e[c]; }
  float ls = __logf(s);
  float inv = 1.f / s;
#pragma unroll
  for (int c = 0; c < C; c++) {
    out_log[(size_t)node * C + c] = lg[c] - m - ls;
    out_soft[(size_t)node * C + c] = e[c] * inv;
  }
}

// ---------------------------------------------------------------------------
extern "C" void kernel_launch(void* const* d_in, const int* in_sizes, int n_in,
                              void* d_out, int out_size, void* d_ws, size_t ws_size,
                              hipStream_t stream) {
  const int N = in_sizes[0] / 128;   // 100000
  const int E = in_sizes[2];         // 1600000

  static const int wn[18] = {16384, 128, 49152, 384, 49152, 384,
                             147456, 147456, 1152, 1152, 49152, 384,
                             256, 2, 768, 6, 2688, 21};
  CvtDesc cd;
  int off = 0;
  for (int i = 0; i < 18; i++) {
    cd.src[i] = d_in[3 + i];
    cd.off[i] = off;
    off += wn[i];
  }
  cd.off[18] = off;
  const int wtotal = off;  // 466077

  // ---- workspace bump allocator (~95 MB) ----
  char* p = (char*)d_ws;
  size_t used = 0;
  auto alloc = [&](size_t bytes) -> char* {
    char* r = p;
    size_t b = (bytes + 255) & ~(size_t)255;
    p += b;
    used += b;
    return r;
  };
  int*      flag   = (int*)alloc(256);
  float*    wbase  = (float*)alloc((size_t)wtotal * 4);
  uint16_t* wb16   = (uint16_t*)alloc((size_t)wtotal * 2);
  uint16_t* xb     = (uint16_t*)alloc((size_t)N * 128 * 2);
  uint16_t* aggb   = (uint16_t*)alloc((size_t)N * 128 * 2);
  uint16_t* hb     = (uint16_t*)alloc((size_t)N * 128 * 2);
  int*      deg    = (int*)alloc((size_t)N * 4);
  int*      rowptr = (int*)alloc((size_t)(N + 1) * 4);
  int*      cursor = (int*)alloc((size_t)N * 4);
  int*      csr_src= (int*)alloc((size_t)E * 4);
  float*    csr_w  = (float*)alloc((size_t)E * 4);
  int*      bsum   = (int*)alloc(4096);

  // FLOAT32 output layout (elements): log0|log1|log2|soft0|soft1|soft2
  float* out = (float*)d_out;
  float* outlog[3]  = {out, out + 2 * (size_t)N, out + 8 * (size_t)N};
  float* outsoft[3] = {out + 29 * (size_t)N, out + 31 * (size_t)N, out + 37 * (size_t)N};

  if (used > ws_size) {
    k_zero_f<<<(out_size + 255) / 256, 256, 0, stream>>>(out, out_size);
    return;
  }

  // f32 (biases, head w2) and bf16 (MFMA weights) views into the arena
  float* b1f   = wbase + cd.off[1];
  float* ginb1 = wbase + cd.off[3];
  float* ginb2 = wbase + cd.off[5];
  float* bih   = wbase + cd.off[8];
  float* bhh   = wbase + cd.off[9];
  float* hb1   = wbase + cd.off[11];
  float* hw2_0 = wbase + cd.off[12];
  float* hb2_0 = wbase + cd.off[13];
  float* hw2_1 = wbase + cd.off[14];
  float* hb2_1 = wbase + cd.off[15];
  float* hw2_2 = wbase + cd.off[16];
  float* hb2_2 = wbase + cd.off[17];

  uint16_t* w1b   = wb16 + cd.off[0];
  uint16_t* ginw1b= wb16 + cd.off[2];
  uint16_t* ginw2b= wb16 + cd.off[4];
  uint16_t* wihb  = wb16 + cd.off[6];
  uint16_t* whhb  = wb16 + cd.off[7];
  uint16_t* hw1b  = wb16 + cd.off[10];

  const int* dst = (const int*)d_in[1];       // edge_index[0]
  const int* src = (const int*)d_in[1] + E;   // edge_index[1]

  // ---- dtype probe + conversions ----
  k_detect<<<1, 64, 0, stream>>>((const uint32_t*)d_in[0], flag);
  k_cvtw<<<(wtotal + 255) / 256, 256, 0, stream>>>(cd, wbase, flag, wtotal);
  k_cvtb<<<(wtotal + 255) / 256, 256, 0, stream>>>(wbase, wb16, wtotal);
  k_cvt_feat<<<((size_t)N * 128 + 255) / 256, 256, 0, stream>>>(d_in[0], aggb,
                                                                N * 128, flag);

  // ---- CSR build ----
  k_zero_i<<<(N + 255) / 256, 256, 0, stream>>>(deg, N);
  k_hist<<<(E + 255) / 256, 256, 0, stream>>>(dst, deg, E);
  int nb = (N + 1023) / 1024;
  k_scan1<<<nb, 256, 0, stream>>>(deg, bsum, N);
  k_scan2<<<1, 64, 0, stream>>>(bsum, nb, rowptr, N);
  k_scan3<<<nb, 256, 0, stream>>>(deg, bsum, rowptr, cursor, N);
  k_scatter<<<(E + 255) / 256, 256, 0, stream>>>(dst, src, d_in[2], cursor,
                                                 csr_src, csr_w, flag, E);

  int mmrb = (N + 63) / 64;    // 64 rows/block (4 waves x 16)
  int grub = (N + 15) / 16;    // 16 rows/block
  int spb  = (N + 3) / 4;
  int hdb  = (N + 255) / 256;

  // mlp1: xb = relu(features(aggb) @ w1^T + b1)
  k_mm<1><<<mmrb, 256, 0, stream>>>(aggb, w1b, b1f, xb, N);

  for (int i = 0; i < 3; i++) {
    k_spmm<<<spb, 256, 0, stream>>>(xb, rowptr, csr_src, csr_w, aggb, N);
    k_gru<<<grub, 256, 0, stream>>>(aggb, xb, wihb + (size_t)i * 384 * 128,
                                    whhb + (size_t)i * 384 * 128,
                                    bih + i * 384, bhh + i * 384, hb, N);
    k_mm<1><<<mmrb, 256, 0, stream>>>(hb, ginw1b + (size_t)i * 128 * 128,
                                      ginb1 + i * 128, aggb, N);
    k_mm<2><<<mmrb, 256, 0, stream>>>(aggb, ginw2b + (size_t)i * 128 * 128,
                                      ginb2 + i * 128, xb, N);
    k_mm<1><<<mmrb, 256, 0, stream>>>(xb, hw1b + (size_t)i * 128 * 128,
                                      hb1 + i * 128, aggb, N);
    if (i == 0)
      k_heads<2><<<hdb, 256, 0, stream>>>(aggb, hw2_0, hb2_0, outlog[0], outsoft[0], N);
    else if (i == 1)
      k_heads<6><<<hdb, 256, 0, stream>>>(aggb, hw2_1, hb2_1, outlog[1], outsoft[1], N);
    else
      k_heads<21><<<hdb, 256, 0, stream>>>(aggb, hw2_2, hb2_2, outlog[2], outsoft[2], N);
  }
}

// Round 10
// 1173.383 us; speedup vs baseline: 17.2868x; 1.3007x over previous
//
#include <hip/hip_runtime.h>
#include <cstdint>
#include <cstddef>

// ---------------------------------------------------------------------------
// GatedGIN forward. Inputs bf16-or-f32 (runtime probe), OUTPUT = FLOAT32.
// Round 10: fragment-major repacked weights (coalesced 1KB B-fragment blocks,
// near-zero address math) + 2x M per wave (each W-fragment feeds 2 MFMAs).
// ---------------------------------------------------------------------------

typedef short  v8s __attribute__((ext_vector_type(8)));
typedef float  v4f __attribute__((ext_vector_type(4)));

static __device__ __forceinline__ float bf2f(uint16_t u) {
  return __uint_as_float(((uint32_t)u) << 16);
}
static __device__ __forceinline__ uint16_t f2b(float f) {
  uint32_t x = __float_as_uint(f);
  return (uint16_t)((x + 0x7FFFu + ((x >> 16) & 1u)) >> 16);
}
static __device__ __forceinline__ float sigmoidf_(float v) {
  return 1.f / (1.f + __expf(-v));
}

// ---------------- dtype probe ----------------
__global__ void k_detect(const uint32_t* __restrict__ u, int* __restrict__ flag) {
  int lane = threadIdx.x;  // 64 threads
  uint32_t low = u[lane] & 0xFFFFu;
  uint32_t e = (low >> 7) & 0xFFu;
  bool pass = (e == 0) || (e >= 110 && e <= 141);
  unsigned long long b = __ballot(pass);
  if (lane == 0) *flag = (__popcll(b) >= 32) ? 1 : 0;
}

// ---------------- upcast weights to f32 workspace ----------------
struct CvtDesc {
  const void* src[18];
  int off[19];
};

__global__ void k_cvtw(CvtDesc c, float* __restrict__ wbase,
                       const int* __restrict__ flag, int total) {
  int gid = blockIdx.x * 256 + threadIdx.x;
  if (gid >= total) return;
  int t = 0;
#pragma unroll
  for (int i = 1; i < 18; i++)
    if (gid >= c.off[i]) t = i;
  int local = gid - c.off[t];
  float v;
  if (*flag) v = bf2f(((const uint16_t*)c.src[t])[local]);
  else       v = ((const float*)c.src[t])[local];
  wbase[gid] = v;
}

// f32 -> bf16 mirror of the weight arena
__global__ void k_cvtb(const float* __restrict__ src, uint16_t* __restrict__ dst,
                       int n) {
  int i = blockIdx.x * 256 + threadIdx.x;
  if (i < n) dst[i] = f2b(src[i]);
}

__global__ void k_cvt_feat(const void* __restrict__ src, uint16_t* __restrict__ dst,
                           int n, const int* __restrict__ flag) {
  int i = blockIdx.x * 256 + threadIdx.x;
  if (i >= n) return;
  if (*flag) dst[i] = ((const uint16_t*)src)[i];
  else       dst[i] = f2b(((const float*)src)[i]);
}

__global__ void k_zero_i(int* __restrict__ p, int n) {
  int i = blockIdx.x * 256 + threadIdx.x;
  if (i < n) p[i] = 0;
}

__global__ void k_zero_f(float* __restrict__ p, int n) {
  int i = blockIdx.x * 256 + threadIdx.x;
  if (i < n) p[i] = 0.f;
}

// ---------------- weight repack: fragment-major for 16x16x32 MFMA ----------
// k_mm layout: blk = kc*8 + t (kc=0..3, t=0..7); block = 64 lanes x 8 bf16.
// dst[(mat*32 + blk)*512 + lane*8 + j] = src[mat*16384 + (t*16+n0)*128 + kc*32 + quad*8 + j]
__global__ void k_pack_mm(const uint16_t* __restrict__ src, uint16_t* __restrict__ dst,
                          int nmat) {
  int id = blockIdx.x * 256 + threadIdx.x;
  if (id >= nmat * 2048) return;
  int mat = id >> 11;
  int rem = id & 2047;
  int blk = rem >> 6, lane = rem & 63;
  int kc = blk >> 3, t = blk & 7;
  int n0 = lane & 15, quad = lane >> 4;
  const uint16_t* s = src + (size_t)mat * 16384 + (size_t)(t * 16 + n0) * 128 + kc * 32 + quad * 8;
  uint16_t* d = dst + (size_t)id * 8;
  *reinterpret_cast<v8s*>(d) = *reinterpret_cast<const v8s*>(s);
}

// GRU layout: blk = (kc*4 + w)*12 + (u*2 + mat)*3 + g  (192 blocks/layer)
// src row = g*128 + w*32 + u*16 + n0 ; col = kc*32 + quad*8 + j
__global__ void k_pack_gru(const uint16_t* __restrict__ wih, const uint16_t* __restrict__ whh,
                           uint16_t* __restrict__ dst, int nlayer) {
  int id = blockIdx.x * 256 + threadIdx.x;
  if (id >= nlayer * 192 * 64) return;
  int lane = id & 63;
  int blk = (id >> 6) % 192;
  int layer = (id >> 6) / 192;
  int g = blk % 3;
  int mat = (blk / 3) % 2;
  int u = (blk / 6) % 2;
  int w = (blk / 12) % 4;
  int kc = blk / 48;
  int n0 = lane & 15, quad = lane >> 4;
  const uint16_t* base = (mat == 0 ? wih : whh) + (size_t)layer * 384 * 128;
  const uint16_t* s = base + (size_t)(g * 128 + w * 32 + u * 16 + n0) * 128 + kc * 32 + quad * 8;
  uint16_t* d = dst + ((size_t)layer * 192 + blk) * 512 + (size_t)lane * 8;
  *reinterpret_cast<v8s*>(d) = *reinterpret_cast<const v8s*>(s);
}

// ---------------- CSR build ----------------
__global__ void k_hist(const int* __restrict__ dst, int* __restrict__ deg, int E) {
  int e = blockIdx.x * 256 + threadIdx.x;
  if (e < E) atomicAdd(&deg[dst[e]], 1);
}

__global__ void k_scan1(const int* __restrict__ deg, int* __restrict__ bsum, int n) {
  __shared__ int red[256];
  int t = threadIdx.x;
  int base = blockIdx.x * 1024;
  int s = 0;
#pragma unroll
  for (int i = 0; i < 4; i++) {
    int idx = base + i * 256 + t;
    if (idx < n) s += deg[idx];
  }
  red[t] = s;
  __syncthreads();
  for (int off = 128; off > 0; off >>= 1) {
    if (t < off) red[t] += red[t + off];
    __syncthreads();
  }
  if (t == 0) bsum[blockIdx.x] = red[0];
}

__global__ void k_scan2(int* bsum, int nb, int* rowptr, int n) {
  if (threadIdx.x == 0 && blockIdx.x == 0) {
    int run = 0;
    for (int b = 0; b < nb; b++) {
      int v = bsum[b];
      bsum[b] = run;
      run += v;
    }
    rowptr[n] = run;  // == E
  }
}

__global__ void k_scan3(const int* __restrict__ deg, const int* __restrict__ bsum,
                        int* __restrict__ rowptr, int* __restrict__ cursor, int n) {
  __shared__ int lds[256];
  int t = threadIdx.x;
  int base = blockIdx.x * 1024 + t * 4;
  int v0 = 0, v1 = 0, v2 = 0, v3 = 0;
  if (base + 0 < n) v0 = deg[base + 0];
  if (base + 1 < n) v1 = deg[base + 1];
  if (base + 2 < n) v2 = deg[base + 2];
  if (base + 3 < n) v3 = deg[base + 3];
  int s = v0 + v1 + v2 + v3;
  lds[t] = s;
  __syncthreads();
  for (int off = 1; off < 256; off <<= 1) {
    int u = (t >= off) ? lds[t - off] : 0;
    __syncthreads();
    lds[t] += u;
    __syncthreads();
  }
  int run = lds[t] - s + bsum[blockIdx.x];
  if (base + 0 < n) { rowptr[base + 0] = run; cursor[base + 0] = run; run += v0; }
  if (base + 1 < n) { rowptr[base + 1] = run; cursor[base + 1] = run; run += v1; }
  if (base + 2 < n) { rowptr[base + 2] = run; cursor[base + 2] = run; run += v2; }
  if (base + 3 < n) { rowptr[base + 3] = run; cursor[base + 3] = run; run += v3; }
}

__global__ void k_scatter(const int* __restrict__ dst, const int* __restrict__ src,
                          const void* __restrict__ w, int* __restrict__ cursor,
                          int* __restrict__ csr_src, float* __restrict__ csr_w,
                          const int* __restrict__ flag, int E) {
  int e = blockIdx.x * 256 + threadIdx.x;
  if (e < E) {
    int d = dst[e];
    int pos = atomicAdd(&cursor[d], 1);
    csr_src[pos] = src[e];
    float wv;
    if (*flag) wv = bf2f(((const uint16_t*)w)[e]);
    else       wv = ((const float*)w)[e];
    csr_w[pos] = wv;
  }
}

// ---------------- SpMM gather: 4 nodes/block, 64 thr/node, ushort2/lane ----
__global__ void k_spmm(const uint16_t* __restrict__ x, const int* __restrict__ rowptr,
                       const int* __restrict__ csr_src, const float* __restrict__ csr_w,
                       uint16_t* __restrict__ agg, int n) {
  int node = blockIdx.x * 4 + (threadIdx.x >> 6);
  int lane = threadIdx.x & 63;
  if (node >= n) return;
  int p0 = rowptr[node], p1 = rowptr[node + 1];
  float a0 = 0.f, a1 = 0.f;
  int p = p0;
  for (; p + 1 < p1; p += 2) {
    int s0 = csr_src[p], s1 = csr_src[p + 1];
    float w0 = csr_w[p], w1 = csr_w[p + 1];
    uint32_t u0 = *reinterpret_cast<const uint32_t*>(x + (size_t)s0 * 128 + lane * 2);
    uint32_t u1 = *reinterpret_cast<const uint32_t*>(x + (size_t)s1 * 128 + lane * 2);
    a0 = fmaf(w0, bf2f((uint16_t)u0), a0);
    a1 = fmaf(w0, bf2f((uint16_t)(u0 >> 16)), a1);
    a0 = fmaf(w1, bf2f((uint16_t)u1), a0);
    a1 = fmaf(w1, bf2f((uint16_t)(u1 >> 16)), a1);
  }
  if (p < p1) {
    float w0 = csr_w[p];
    uint32_t u0 = *reinterpret_cast<const uint32_t*>(x + (size_t)csr_src[p] * 128 + lane * 2);
    a0 = fmaf(w0, bf2f((uint16_t)u0), a0);
    a1 = fmaf(w0, bf2f((uint16_t)(u0 >> 16)), a1);
  }
  uint32_t packed = (uint32_t)f2b(a0) | ((uint32_t)f2b(a1) << 16);
  *reinterpret_cast<uint32_t*>(agg + (size_t)node * 128 + lane * 2) = packed;
}

// ---------------- MFMA matmul, repacked W, 32 rows/wave ----------
// EPI 1 = relu; EPI 2 = relu + row-norm. Out bf16. Block = 4 waves = 128 rows.
template <int EPI>
__launch_bounds__(256)
__global__ void k_mm(const uint16_t* __restrict__ A, const uint16_t* __restrict__ Wrp,
                     const float* __restrict__ bias, uint16_t* __restrict__ C,
                     int nrows) {
  int wave = threadIdx.x >> 6, lane = threadIdx.x & 63;
  int n0 = lane & 15, quad = lane >> 4;
  int m0 = (blockIdx.x * 4 + wave) * 32;
  int r0 = m0 + n0, r1 = m0 + 16 + n0;
  bool ok0 = r0 < nrows, ok1 = r1 < nrows;
  const v8s z8 = {0, 0, 0, 0, 0, 0, 0, 0};

  v4f acc[2][8];
#pragma unroll
  for (int rt = 0; rt < 2; rt++)
#pragma unroll
    for (int t = 0; t < 8; t++) acc[rt][t] = {0.f, 0.f, 0.f, 0.f};

  const uint16_t* ap0 = A + (size_t)r0 * 128 + quad * 8;
  const uint16_t* ap1 = A + (size_t)r1 * 128 + quad * 8;
#pragma unroll
  for (int kc = 0; kc < 4; kc++) {
    v8s a0 = ok0 ? *reinterpret_cast<const v8s*>(ap0 + kc * 32) : z8;
    v8s a1 = ok1 ? *reinterpret_cast<const v8s*>(ap1 + kc * 32) : z8;
    const uint16_t* wp = Wrp + (size_t)kc * 4096 + (size_t)lane * 8;
#pragma unroll
    for (int t = 0; t < 8; t++) {
      v8s bf = *reinterpret_cast<const v8s*>(wp + t * 512);
      acc[0][t] = __builtin_amdgcn_mfma_f32_16x16x32_bf16(a0, bf, acc[0][t], 0, 0, 0);
      acc[1][t] = __builtin_amdgcn_mfma_f32_16x16x32_bf16(a1, bf, acc[1][t], 0, 0, 0);
    }
  }

#pragma unroll
  for (int rt = 0; rt < 2; rt++) {
    int mb = m0 + rt * 16;
    float vv[8][4];
#pragma unroll
    for (int t = 0; t < 8; t++) {
      float b = bias[t * 16 + n0];
#pragma unroll
      for (int r = 0; r < 4; r++) vv[t][r] = fmaxf(acc[rt][t][r] + b, 0.f);
    }
    if (EPI == 2) {
#pragma unroll
      for (int r = 0; r < 4; r++) {
        float ss = 0.f;
#pragma unroll
        for (int t = 0; t < 8; t++) ss = fmaf(vv[t][r], vv[t][r], ss);
        ss += __shfl_xor(ss, 1);
        ss += __shfl_xor(ss, 2);
        ss += __shfl_xor(ss, 4);
        ss += __shfl_xor(ss, 8);
        float sc = rsqrtf(1.f + ss);
#pragma unroll
        for (int t = 0; t < 8; t++) vv[t][r] *= sc;
      }
    }
#pragma unroll
    for (int r = 0; r < 4; r++) {
      int row = mb + quad * 4 + r;
      if (row >= nrows) continue;
#pragma unroll
      for (int t = 0; t < 8; t++)
        C[(size_t)row * 128 + t * 16 + n0] = f2b(vv[t][r]);
    }
  }
}

// ---------------- MFMA fused GRU, repacked W, 32 rows/block ----------------
// Block 256 = 4 waves over the SAME 32 rows; wave w covers h-cols [32w,32w+32).
__launch_bounds__(256)
__global__ void k_gru(const uint16_t* __restrict__ aggb, const uint16_t* __restrict__ xb,
                      const uint16_t* __restrict__ Wrp,
                      const float* __restrict__ bih, const float* __restrict__ bhh,
                      uint16_t* __restrict__ hb, int n) {
  int wave = threadIdx.x >> 6, lane = threadIdx.x & 63;
  int n0 = lane & 15, quad = lane >> 4;
  int m0 = blockIdx.x * 32;
  int r0 = m0 + n0, r1 = m0 + 16 + n0;
  bool ok0 = r0 < n, ok1 = r1 < n;
  const v8s z8 = {0, 0, 0, 0, 0, 0, 0, 0};

  v4f accI[2][2][3], accH[2][2][3];  // [rowtile][u][gate]
#pragma unroll
  for (int rt = 0; rt < 2; rt++)
#pragma unroll
    for (int u = 0; u < 2; u++)
#pragma unroll
      for (int g = 0; g < 3; g++) {
        accI[rt][u][g] = {0.f, 0.f, 0.f, 0.f};
        accH[rt][u][g] = {0.f, 0.f, 0.f, 0.f};
      }

  const uint16_t* ap0 = aggb + (size_t)r0 * 128 + quad * 8;
  const uint16_t* ap1 = aggb + (size_t)r1 * 128 + quad * 8;
  const uint16_t* xp0 = xb + (size_t)r0 * 128 + quad * 8;
  const uint16_t* xp1 = xb + (size_t)r1 * 128 + quad * 8;
#pragma unroll
  for (int kc = 0; kc < 4; kc++) {
    v8s a0 = ok0 ? *reinterpret_cast<const v8s*>(ap0 + kc * 32) : z8;
    v8s a1 = ok1 ? *reinterpret_cast<const v8s*>(ap1 + kc * 32) : z8;
    v8s x0 = ok0 ? *reinterpret_cast<const v8s*>(xp0 + kc * 32) : z8;
    v8s x1 = ok1 ? *reinterpret_cast<const v8s*>(xp1 + kc * 32) : z8;
    const uint16_t* wp = Wrp + (size_t)((kc * 4 + wave) * 12) * 512 + (size_t)lane * 8;
#pragma unroll
    for (int u = 0; u < 2; u++) {
#pragma unroll
      for (int g = 0; g < 3; g++) {
        v8s bi = *reinterpret_cast<const v8s*>(wp + (u * 6 + g) * 512);
        v8s bh = *reinterpret_cast<const v8s*>(wp + (u * 6 + 3 + g) * 512);
        accI[0][u][g] = __builtin_amdgcn_mfma_f32_16x16x32_bf16(a0, bi, accI[0][u][g], 0, 0, 0);
        accI[1][u][g] = __builtin_amdgcn_mfma_f32_16x16x32_bf16(a1, bi, accI[1][u][g], 0, 0, 0);
        accH[0][u][g] = __builtin_amdgcn_mfma_f32_16x16x32_bf16(x0, bh, accH[0][u][g], 0, 0, 0);
        accH[1][u][g] = __builtin_amdgcn_mfma_f32_16x16x32_bf16(x1, bh, accH[1][u][g], 0, 0, 0);
      }
    }
  }

  // gates epilogue: lane holds rows m0 + rt*16 + quad*4 + r, col = wave*32 + u*16 + n0
#pragma unroll
  for (int rt = 0; rt < 2; rt++) {
#pragma unroll
    for (int u = 0; u < 2; u++) {
      int col = wave * 32 + u * 16 + n0;
      float bir = bih[col], biz = bih[128 + col], bin = bih[256 + col];
      float bhr = bhh[col], bhz = bhh[128 + col], bhn = bhh[256 + col];
#pragma unroll
      for (int r = 0; r < 4; r++) {
        int row = m0 + rt * 16 + quad * 4 + r;
        if (row >= n) continue;
        float ir = accI[rt][u][0][r] + bir;
        float iz = accI[rt][u][1][r] + biz;
        float in_ = accI[rt][u][2][r] + bin;
        float hr = accH[rt][u][0][r] + bhr;
        float hz = accH[rt][u][1][r] + bhz;
        float hn = accH[rt][u][2][r] + bhn;
        float rr = sigmoidf_(ir + hr);
        float zz = sigmoidf_(iz + hz);
        float nn = tanhf(fmaf(rr, hn, in_));
        float xv = bf2f(xb[(size_t)row * 128 + col]);
        hb[(size_t)row * 128 + col] = f2b(fmaf(zz, xv - nn, nn));
      }
    }
  }
}

// ---------------- head: one thread per node, FLOAT32 output ----------------
template <int C>
__global__ void k_heads(const uint16_t* __restrict__ hh, const float* __restrict__ w2,
                        const float* __restrict__ b2,
                        float* __restrict__ out_log, float* __restrict__ out_soft,
                        int n) {
  int node = blockIdx.x * 256 + threadIdx.x;
  if (node >= n) return;
  const uint16_t* row = hh + (size_t)node * 128;
  float lg[C];
#pragma unroll
  for (int c = 0; c < C; c++) lg[c] = b2[c];
  for (int k = 0; k < 128; k++) {
    float xv = bf2f(row[k]);
#pragma unroll
    for (int c = 0; c < C; c++) lg[c] = fmaf(xv, w2[c * 128 + k], lg[c]);
  }
  float m = lg[0];
#pragma unroll
  for (int c = 1; c < C; c++) m = fmaxf(m, lg[c]);
  float s = 0.f;
  float e[C];
#pragma unroll
  for (int c = 0; c < C; c++) { e[c] = __expf(lg[c] - m); s += e[c]; }
  float ls = __logf(s);
  float inv = 1.f / s;
#pragma unroll
  for (int c = 0; c < C; c++) {
    out_log[(size_t)node * C + c] = lg[c] - m - ls;
    out_soft[(size_t)node * C + c] = e[c] * inv;
  }
}

// ---------------------------------------------------------------------------
extern "C" void kernel_launch(void* const* d_in, const int* in_sizes, int n_in,
                              void* d_out, int out_size, void* d_ws, size_t ws_size,
                              hipStream_t stream) {
  const int N = in_sizes[0] / 128;   // 100000
  const int E = in_sizes[2];         // 1600000

  static const int wn[18] = {16384, 128, 49152, 384, 49152, 384,
                             147456, 147456, 1152, 1152, 49152, 384,
                             256, 2, 768, 6, 2688, 21};
  CvtDesc cd;
  int off = 0;
  for (int i = 0; i < 18; i++) {
    cd.src[i] = d_in[3 + i];
    cd.off[i] = off;
    off += wn[i];
  }
  cd.off[18] = off;
  const int wtotal = off;  // 466077

  // ---- workspace bump allocator (~96 MB) ----
  char* p = (char*)d_ws;
  size_t used = 0;
  auto alloc = [&](size_t bytes) -> char* {
    char* r = p;
    size_t b = (bytes + 255) & ~(size_t)255;
    p += b;
    used += b;
    return r;
  };
  int*      flag   = (int*)alloc(256);
  float*    wbase  = (float*)alloc((size_t)wtotal * 4);
  uint16_t* wb16   = (uint16_t*)alloc((size_t)wtotal * 2);
  uint16_t* mmrp   = (uint16_t*)alloc((size_t)10 * 16384 * 2);      // repacked mm W
  uint16_t* grurp  = (uint16_t*)alloc((size_t)3 * 192 * 512 * 2);   // repacked gru W
  uint16_t* xb     = (uint16_t*)alloc((size_t)N * 128 * 2);
  uint16_t* aggb   = (uint16_t*)alloc((size_t)N * 128 * 2);
  uint16_t* hb     = (uint16_t*)alloc((size_t)N * 128 * 2);
  int*      deg    = (int*)alloc((size_t)N * 4);
  int*      rowptr = (int*)alloc((size_t)(N + 1) * 4);
  int*      cursor = (int*)alloc((size_t)N * 4);
  int*      csr_src= (int*)alloc((size_t)E * 4);
  float*    csr_w  = (float*)alloc((size_t)E * 4);
  int*      bsum   = (int*)alloc(4096);

  // FLOAT32 output layout (elements): log0|log1|log2|soft0|soft1|soft2
  float* out = (float*)d_out;
  float* outlog[3]  = {out, out + 2 * (size_t)N, out + 8 * (size_t)N};
  float* outsoft[3] = {out + 29 * (size_t)N, out + 31 * (size_t)N, out + 37 * (size_t)N};

  if (used > ws_size) {
    k_zero_f<<<(out_size + 255) / 256, 256, 0, stream>>>(out, out_size);
    return;
  }

  float* b1f   = wbase + cd.off[1];
  float* ginb1 = wbase + cd.off[3];
  float* ginb2 = wbase + cd.off[5];
  float* bih   = wbase + cd.off[8];
  float* bhh   = wbase + cd.off[9];
  float* hb1   = wbase + cd.off[11];
  float* hw2_0 = wbase + cd.off[12];
  float* hb2_0 = wbase + cd.off[13];
  float* hw2_1 = wbase + cd.off[14];
  float* hb2_1 = wbase + cd.off[15];
  float* hw2_2 = wbase + cd.off[16];
  float* hb2_2 = wbase + cd.off[17];

  uint16_t* w1b   = wb16 + cd.off[0];
  uint16_t* ginw1b= wb16 + cd.off[2];
  uint16_t* ginw2b= wb16 + cd.off[4];
  uint16_t* wihb  = wb16 + cd.off[6];
  uint16_t* whhb  = wb16 + cd.off[7];
  uint16_t* hw1b  = wb16 + cd.off[10];

  // repacked views: [0]=w1, [1+i]=ginw1_i, [4+i]=ginw2_i, [7+i]=hw1_i
  uint16_t* w1rp    = mmrp;
  uint16_t* ginw1rp = mmrp + (size_t)1 * 16384;
  uint16_t* ginw2rp = mmrp + (size_t)4 * 16384;
  uint16_t* hw1rp   = mmrp + (size_t)7 * 16384;

  const int* dst = (const int*)d_in[1];       // edge_index[0]
  const int* src = (const int*)d_in[1] + E;   // edge_index[1]

  // ---- dtype probe + conversions + repack ----
  k_detect<<<1, 64, 0, stream>>>((const uint32_t*)d_in[0], flag);
  k_cvtw<<<(wtotal + 255) / 256, 256, 0, stream>>>(cd, wbase, flag, wtotal);
  k_cvtb<<<(wtotal + 255) / 256, 256, 0, stream>>>(wbase, wb16, wtotal);
  k_cvt_feat<<<((size_t)N * 128 + 255) / 256, 256, 0, stream>>>(d_in[0], aggb,
                                                                N * 128, flag);
  k_pack_mm<<<(1 * 2048 + 255) / 256, 256, 0, stream>>>(w1b, w1rp, 1);
  k_pack_mm<<<(3 * 2048 + 255) / 256, 256, 0, stream>>>(ginw1b, ginw1rp, 3);
  k_pack_mm<<<(3 * 2048 + 255) / 256, 256, 0, stream>>>(ginw2b, ginw2rp, 3);
  k_pack_mm<<<(3 * 2048 + 255) / 256, 256, 0, stream>>>(hw1b, hw1rp, 3);
  k_pack_gru<<<(3 * 192 * 64 + 255) / 256, 256, 0, stream>>>(wihb, whhb, grurp, 3);

  // ---- CSR build ----
  k_zero_i<<<(N + 255) / 256, 256, 0, stream>>>(deg, N);
  k_hist<<<(E + 255) / 256, 256, 0, stream>>>(dst, deg, E);
  int nb = (N + 1023) / 1024;
  k_scan1<<<nb, 256, 0, stream>>>(deg, bsum, N);
  k_scan2<<<1, 64, 0, stream>>>(bsum, nb, rowptr, N);
  k_scan3<<<nb, 256, 0, stream>>>(deg, bsum, rowptr, cursor, N);
  k_scatter<<<(E + 255) / 256, 256, 0, stream>>>(dst, src, d_in[2], cursor,
                                                 csr_src, csr_w, flag, E);

  int mmrb = (N + 127) / 128;  // 128 rows/block (4 waves x 32)
  int grub = (N + 31) / 32;    // 32 rows/block
  int spb  = (N + 3) / 4;
  int hdb  = (N + 255) / 256;

  // mlp1: xb = relu(features(aggb) @ w1^T + b1)
  k_mm<1><<<mmrb, 256, 0, stream>>>(aggb, w1rp, b1f, xb, N);

  for (int i = 0; i < 3; i++) {
    k_spmm<<<spb, 256, 0, stream>>>(xb, rowptr, csr_src, csr_w, aggb, N);
    k_gru<<<grub, 256, 0, stream>>>(aggb, xb, grurp + (size_t)i * 192 * 512,
                                    bih + i * 384, bhh + i * 384, hb, N);
    k_mm<1><<<mmrb, 256, 0, stream>>>(hb, ginw1rp + (size_t)i * 16384,
                                      ginb1 + i * 128, aggb, N);
    k_mm<2><<<mmrb, 256, 0, stream>>>(aggb, ginw2rp + (size_t)i * 16384,
                                      ginb2 + i * 128, xb, N);
    k_mm<1><<<mmrb, 256, 0, stream>>>(xb, hw1rp + (size_t)i * 16384,
                                      hb1 + i * 128, aggb, N);
    if (i == 0)
      k_heads<2><<<hdb, 256, 0, stream>>>(aggb, hw2_0, hb2_0, outlog[0], outsoft[0], N);
    else if (i == 1)
      k_heads<6><<<hdb, 256, 0, stream>>>(aggb, hw2_1, hb2_1, outlog[1], outsoft[1], N);
    else
      k_heads<21><<<hdb, 256, 0, stream>>>(aggb, hw2_2, hb2_2, outlog[2], outsoft[2], N);
  }
}

// Round 11
// 1096.367 us; speedup vs baseline: 18.5011x; 1.0702x over previous
//
#include <hip/hip_runtime.h>
#include <cstdint>
#include <cstddef>

// ---------------------------------------------------------------------------
// GatedGIN forward. Inputs bf16-or-f32 (runtime probe), OUTPUT = FLOAT32.
// Round 11: (1) edge payload packed to one uint2 (halves random-write
// cachelines in scatter), (2) GRU+GIN1 fused via LDS h-tile (hb eliminated),
// (3) merged weight-convert, spmm unroll-4.
// ---------------------------------------------------------------------------

typedef short  v8s __attribute__((ext_vector_type(8)));
typedef float  v4f __attribute__((ext_vector_type(4)));

static __device__ __forceinline__ float bf2f(uint16_t u) {
  return __uint_as_float(((uint32_t)u) << 16);
}
static __device__ __forceinline__ uint16_t f2b(float f) {
  uint32_t x = __float_as_uint(f);
  return (uint16_t)((x + 0x7FFFu + ((x >> 16) & 1u)) >> 16);
}
static __device__ __forceinline__ float sigmoidf_(float v) {
  return 1.f / (1.f + __expf(-v));
}

// ---------------- dtype probe ----------------
__global__ void k_detect(const uint32_t* __restrict__ u, int* __restrict__ flag) {
  int lane = threadIdx.x;  // 64 threads
  uint32_t low = u[lane] & 0xFFFFu;
  uint32_t e = (low >> 7) & 0xFFu;
  bool pass = (e == 0) || (e >= 110 && e <= 141);
  unsigned long long b = __ballot(pass);
  if (lane == 0) *flag = (__popcll(b) >= 32) ? 1 : 0;
}

// ---------------- weight convert: one pass -> f32 arena + bf16 arena -------
struct CvtDesc {
  const void* src[18];
  int off[19];
};

__global__ void k_cvtw(CvtDesc c, float* __restrict__ wbase,
                       uint16_t* __restrict__ wb16,
                       const int* __restrict__ flag, int total) {
  int gid = blockIdx.x * 256 + threadIdx.x;
  if (gid >= total) return;
  int t = 0;
#pragma unroll
  for (int i = 1; i < 18; i++)
    if (gid >= c.off[i]) t = i;
  int local = gid - c.off[t];
  float v;
  if (*flag) v = bf2f(((const uint16_t*)c.src[t])[local]);
  else       v = ((const float*)c.src[t])[local];
  wbase[gid] = v;
  wb16[gid] = f2b(v);
}

__global__ void k_cvt_feat(const void* __restrict__ src, uint16_t* __restrict__ dst,
                           int n, const int* __restrict__ flag) {
  int i = blockIdx.x * 256 + threadIdx.x;
  if (i >= n) return;
  if (*flag) dst[i] = ((const uint16_t*)src)[i];
  else       dst[i] = f2b(((const float*)src)[i]);
}

__global__ void k_zero_i(int* __restrict__ p, int n) {
  int i = blockIdx.x * 256 + threadIdx.x;
  if (i < n) p[i] = 0;
}

__global__ void k_zero_f(float* __restrict__ p, int n) {
  int i = blockIdx.x * 256 + threadIdx.x;
  if (i < n) p[i] = 0.f;
}

// ---------------- weight repack: fragment-major for 16x16x32 MFMA ----------
__global__ void k_pack_mm(const uint16_t* __restrict__ src, uint16_t* __restrict__ dst,
                          int nmat) {
  int id = blockIdx.x * 256 + threadIdx.x;
  if (id >= nmat * 2048) return;
  int mat = id >> 11;
  int rem = id & 2047;
  int blk = rem >> 6, lane = rem & 63;
  int kc = blk >> 3, t = blk & 7;
  int n0 = lane & 15, quad = lane >> 4;
  const uint16_t* s = src + (size_t)mat * 16384 + (size_t)(t * 16 + n0) * 128 + kc * 32 + quad * 8;
  uint16_t* d = dst + (size_t)id * 8;
  *reinterpret_cast<v8s*>(d) = *reinterpret_cast<const v8s*>(s);
}

// GRU layout: blk = (kc*4 + w)*12 + (u*2 + mat)*3 + g  (192 blocks/layer)
__global__ void k_pack_gru(const uint16_t* __restrict__ wih, const uint16_t* __restrict__ whh,
                           uint16_t* __restrict__ dst, int nlayer) {
  int id = blockIdx.x * 256 + threadIdx.x;
  if (id >= nlayer * 192 * 64) return;
  int lane = id & 63;
  int blk = (id >> 6) % 192;
  int layer = (id >> 6) / 192;
  int g = blk % 3;
  int mat = (blk / 3) % 2;
  int u = (blk / 6) % 2;
  int w = (blk / 12) % 4;
  int kc = blk / 48;
  int n0 = lane & 15, quad = lane >> 4;
  const uint16_t* base = (mat == 0 ? wih : whh) + (size_t)layer * 384 * 128;
  const uint16_t* s = base + (size_t)(g * 128 + w * 32 + u * 16 + n0) * 128 + kc * 32 + quad * 8;
  uint16_t* d = dst + ((size_t)layer * 192 + blk) * 512 + (size_t)lane * 8;
  *reinterpret_cast<v8s*>(d) = *reinterpret_cast<const v8s*>(s);
}

// ---------------- CSR build ----------------
__global__ void k_hist(const int* __restrict__ dst, int* __restrict__ deg, int E) {
  int e = blockIdx.x * 256 + threadIdx.x;
  if (e < E) atomicAdd(&deg[dst[e]], 1);
}

__global__ void k_scan1(const int* __restrict__ deg, int* __restrict__ bsum, int n) {
  __shared__ int red[256];
  int t = threadIdx.x;
  int base = blockIdx.x * 1024;
  int s = 0;
#pragma unroll
  for (int i = 0; i < 4; i++) {
    int idx = base + i * 256 + t;
    if (idx < n) s += deg[idx];
  }
  red[t] = s;
  __syncthreads();
  for (int off = 128; off > 0; off >>= 1) {
    if (t < off) red[t] += red[t + off];
    __syncthreads();
  }
  if (t == 0) bsum[blockIdx.x] = red[0];
}

__global__ void k_scan2(int* bsum, int nb, int* rowptr, int n) {
  if (threadIdx.x == 0 && blockIdx.x == 0) {
    int run = 0;
    for (int b = 0; b < nb; b++) {
      int v = bsum[b];
      bsum[b] = run;
      run += v;
    }
    rowptr[n] = run;  // == E
  }
}

__global__ void k_scan3(const int* __restrict__ deg, const int* __restrict__ bsum,
                        int* __restrict__ rowptr, int* __restrict__ cursor, int n) {
  __shared__ int lds[256];
  int t = threadIdx.x;
  int base = blockIdx.x * 1024 + t * 4;
  int v0 = 0, v1 = 0, v2 = 0, v3 = 0;
  if (base + 0 < n) v0 = deg[base + 0];
  if (base + 1 < n) v1 = deg[base + 1];
  if (base + 2 < n) v2 = deg[base + 2];
  if (base + 3 < n) v3 = deg[base + 3];
  int s = v0 + v1 + v2 + v3;
  lds[t] = s;
  __syncthreads();
  for (int off = 1; off < 256; off <<= 1) {
    int u = (t >= off) ? lds[t - off] : 0;
    __syncthreads();
    lds[t] += u;
    __syncthreads();
  }
  int run = lds[t] - s + bsum[blockIdx.x];
  if (base + 0 < n) { rowptr[base + 0] = run; cursor[base + 0] = run; run += v0; }
  if (base + 1 < n) { rowptr[base + 1] = run; cursor[base + 1] = run; run += v1; }
  if (base + 2 < n) { rowptr[base + 2] = run; cursor[base + 2] = run; run += v2; }
  if (base + 3 < n) { rowptr[base + 3] = run; cursor[base + 3] = run; run += v3; }
}

// packed edge payload: .x = src node, .y = weight bits (f32)
__global__ void k_scatter(const int* __restrict__ dst, const int* __restrict__ src,
                          const void* __restrict__ w, int* __restrict__ cursor,
                          uint2* __restrict__ ep, const int* __restrict__ flag, int E) {
  int e = blockIdx.x * 256 + threadIdx.x;
  if (e < E) {
    int d = dst[e];
    int pos = atomicAdd(&cursor[d], 1);
    float wv;
    if (*flag) wv = bf2f(((const uint16_t*)w)[e]);
    else       wv = ((const float*)w)[e];
    ep[pos] = make_uint2((uint32_t)src[e], __float_as_uint(wv));
  }
}

// ---------------- SpMM gather: 4 nodes/block, 64 thr/node, unroll 4 --------
__global__ void k_spmm(const uint16_t* __restrict__ x, const int* __restrict__ rowptr,
                       const uint2* __restrict__ ep, uint16_t* __restrict__ agg, int n) {
  int node = blockIdx.x * 4 + (threadIdx.x >> 6);
  int lane = threadIdx.x & 63;
  if (node >= n) return;
  int p0 = rowptr[node], p1 = rowptr[node + 1];
  float a0 = 0.f, a1 = 0.f;
  int p = p0;
  for (; p + 3 < p1; p += 4) {
    uint2 e0 = ep[p], e1 = ep[p + 1], e2 = ep[p + 2], e3 = ep[p + 3];
    uint32_t u0 = *reinterpret_cast<const uint32_t*>(x + (size_t)e0.x * 128 + lane * 2);
    uint32_t u1 = *reinterpret_cast<const uint32_t*>(x + (size_t)e1.x * 128 + lane * 2);
    uint32_t u2 = *reinterpret_cast<const uint32_t*>(x + (size_t)e2.x * 128 + lane * 2);
    uint32_t u3 = *reinterpret_cast<const uint32_t*>(x + (size_t)e3.x * 128 + lane * 2);
    float w0 = __uint_as_float(e0.y), w1 = __uint_as_float(e1.y);
    float w2 = __uint_as_float(e2.y), w3 = __uint_as_float(e3.y);
    a0 = fmaf(w0, bf2f((uint16_t)u0), a0);
    a1 = fmaf(w0, bf2f((uint16_t)(u0 >> 16)), a1);
    a0 = fmaf(w1, bf2f((uint16_t)u1), a0);
    a1 = fmaf(w1, bf2f((uint16_t)(u1 >> 16)), a1);
    a0 = fmaf(w2, bf2f((uint16_t)u2), a0);
    a1 = fmaf(w2, bf2f((uint16_t)(u2 >> 16)), a1);
    a0 = fmaf(w3, bf2f((uint16_t)u3), a0);
    a1 = fmaf(w3, bf2f((uint16_t)(u3 >> 16)), a1);
  }
  for (; p < p1; p++) {
    uint2 e0 = ep[p];
    float w0 = __uint_as_float(e0.y);
    uint32_t u0 = *reinterpret_cast<const uint32_t*>(x + (size_t)e0.x * 128 + lane * 2);
    a0 = fmaf(w0, bf2f((uint16_t)u0), a0);
    a1 = fmaf(w0, bf2f((uint16_t)(u0 >> 16)), a1);
  }
  uint32_t packed = (uint32_t)f2b(a0) | ((uint32_t)f2b(a1) << 16);
  *reinterpret_cast<uint32_t*>(agg + (size_t)node * 128 + lane * 2) = packed;
}

// ---------------- MFMA matmul, repacked W, 32 rows/wave ----------
// EPI 1 = relu; EPI 2 = relu + row-norm. Out bf16. Block = 4 waves = 128 rows.
template <int EPI>
__launch_bounds__(256)
__global__ void k_mm(const uint16_t* __restrict__ A, const uint16_t* __restrict__ Wrp,
                     const float* __restrict__ bias, uint16_t* __restrict__ C,
                     int nrows) {
  int wave = threadIdx.x >> 6, lane = threadIdx.x & 63;
  int n0 = lane & 15, quad = lane >> 4;
  int m0 = (blockIdx.x * 4 + wave) * 32;
  int r0 = m0 + n0, r1 = m0 + 16 + n0;
  bool ok0 = r0 < nrows, ok1 = r1 < nrows;
  const v8s z8 = {0, 0, 0, 0, 0, 0, 0, 0};

  v4f acc[2][8];
#pragma unroll
  for (int rt = 0; rt < 2; rt++)
#pragma unroll
    for (int t = 0; t < 8; t++) acc[rt][t] = {0.f, 0.f, 0.f, 0.f};

  const uint16_t* ap0 = A + (size_t)r0 * 128 + quad * 8;
  const uint16_t* ap1 = A + (size_t)r1 * 128 + quad * 8;
#pragma unroll
  for (int kc = 0; kc < 4; kc++) {
    v8s a0 = ok0 ? *reinterpret_cast<const v8s*>(ap0 + kc * 32) : z8;
    v8s a1 = ok1 ? *reinterpret_cast<const v8s*>(ap1 + kc * 32) : z8;
    const uint16_t* wp = Wrp + (size_t)kc * 4096 + (size_t)lane * 8;
#pragma unroll
    for (int t = 0; t < 8; t++) {
      v8s bf = *reinterpret_cast<const v8s*>(wp + t * 512);
      acc[0][t] = __builtin_amdgcn_mfma_f32_16x16x32_bf16(a0, bf, acc[0][t], 0, 0, 0);
      acc[1][t] = __builtin_amdgcn_mfma_f32_16x16x32_bf16(a1, bf, acc[1][t], 0, 0, 0);
    }
  }

#pragma unroll
  for (int rt = 0; rt < 2; rt++) {
    int mb = m0 + rt * 16;
    float vv[8][4];
#pragma unroll
    for (int t = 0; t < 8; t++) {
      float b = bias[t * 16 + n0];
#pragma unroll
      for (int r = 0; r < 4; r++) vv[t][r] = fmaxf(acc[rt][t][r] + b, 0.f);
    }
    if (EPI == 2) {
#pragma unroll
      for (int r = 0; r < 4; r++) {
        float ss = 0.f;
#pragma unroll
        for (int t = 0; t < 8; t++) ss = fmaf(vv[t][r], vv[t][r], ss);
        ss += __shfl_xor(ss, 1);
        ss += __shfl_xor(ss, 2);
        ss += __shfl_xor(ss, 4);
        ss += __shfl_xor(ss, 8);
        float sc = rsqrtf(1.f + ss);
#pragma unroll
        for (int t = 0; t < 8; t++) vv[t][r] *= sc;
      }
    }
#pragma unroll
    for (int r = 0; r < 4; r++) {
      int row = mb + quad * 4 + r;
      if (row >= nrows) continue;
#pragma unroll
      for (int t = 0; t < 8; t++)
        C[(size_t)row * 128 + t * 16 + n0] = f2b(vv[t][r]);
    }
  }
}

// ---------------- fused GRU + GIN-mlp1, 32 rows/block ----------------
// Phase 1: GRU (as round-10) -> h into padded LDS tile (32x136 bf16, 8.5KB).
// Phase 2: hid = relu(h @ ginw1^T + gb1) via MFMA, A-frags from LDS,
// B-frags from k_pack_mm-repacked ginw1. hid stored IN-PLACE to agg buffer
// (each block touches only its own 32 rows; phase-1 reads complete before
// the barrier). h never touches global memory.
__launch_bounds__(256)
__global__ void k_grug(const uint16_t* aggio, const uint16_t* __restrict__ xb,
                       const uint16_t* __restrict__ Wrp,
                       const uint16_t* __restrict__ G1rp,
                       const float* __restrict__ bih, const float* __restrict__ bhh,
                       const float* __restrict__ gb1,
                       uint16_t* hidout, int n) {
  __shared__ uint16_t hl[32][136];  // pad 8 bf16 -> 2-way max bank aliasing
  int wave = threadIdx.x >> 6, lane = threadIdx.x & 63;
  int n0 = lane & 15, quad = lane >> 4;
  int m0 = blockIdx.x * 32;
  int r0 = m0 + n0, r1 = m0 + 16 + n0;
  bool ok0 = r0 < n, ok1 = r1 < n;
  const v8s z8 = {0, 0, 0, 0, 0, 0, 0, 0};

  v4f accI[2][2][3], accH[2][2][3];  // [rowtile][u][gate]
#pragma unroll
  for (int rt = 0; rt < 2; rt++)
#pragma unroll
    for (int u = 0; u < 2; u++)
#pragma unroll
      for (int g = 0; g < 3; g++) {
        accI[rt][u][g] = {0.f, 0.f, 0.f, 0.f};
        accH[rt][u][g] = {0.f, 0.f, 0.f, 0.f};
      }

  const uint16_t* ap0 = aggio + (size_t)r0 * 128 + quad * 8;
  const uint16_t* ap1 = aggio + (size_t)r1 * 128 + quad * 8;
  const uint16_t* xp0 = xb + (size_t)r0 * 128 + quad * 8;
  const uint16_t* xp1 = xb + (size_t)r1 * 128 + quad * 8;
#pragma unroll
  for (int kc = 0; kc < 4; kc++) {
    v8s a0 = ok0 ? *reinterpret_cast<const v8s*>(ap0 + kc * 32) : z8;
    v8s a1 = ok1 ? *reinterpret_cast<const v8s*>(ap1 + kc * 32) : z8;
    v8s x0 = ok0 ? *reinterpret_cast<const v8s*>(xp0 + kc * 32) : z8;
    v8s x1 = ok1 ? *reinterpret_cast<const v8s*>(xp1 + kc * 32) : z8;
    const uint16_t* wp = Wrp + (size_t)((kc * 4 + wave) * 12) * 512 + (size_t)lane * 8;
#pragma unroll
    for (int u = 0; u < 2; u++) {
#pragma unroll
      for (int g = 0; g < 3; g++) {
        v8s bi = *reinterpret_cast<const v8s*>(wp + (u * 6 + g) * 512);
        v8s bh = *reinterpret_cast<const v8s*>(wp + (u * 6 + 3 + g) * 512);
        accI[0][u][g] = __builtin_amdgcn_mfma_f32_16x16x32_bf16(a0, bi, accI[0][u][g], 0, 0, 0);
        accI[1][u][g] = __builtin_amdgcn_mfma_f32_16x16x32_bf16(a1, bi, accI[1][u][g], 0, 0, 0);
        accH[0][u][g] = __builtin_amdgcn_mfma_f32_16x16x32_bf16(x0, bh, accH[0][u][g], 0, 0, 0);
        accH[1][u][g] = __builtin_amdgcn_mfma_f32_16x16x32_bf16(x1, bh, accH[1][u][g], 0, 0, 0);
      }
    }
  }

  // gates epilogue -> LDS (rows of this block only; OOB rows get finite junk
  // that only pollutes discarded output rows)
#pragma unroll
  for (int rt = 0; rt < 2; rt++) {
#pragma unroll
    for (int u = 0; u < 2; u++) {
      int col = wave * 32 + u * 16 + n0;
      float bir = bih[col], biz = bih[128 + col], bin = bih[256 + col];
      float bhr = bhh[col], bhz = bhh[128 + col], bhn = bhh[256 + col];
#pragma unroll
      for (int r = 0; r < 4; r++) {
        int rl = rt * 16 + quad * 4 + r;
        int row = m0 + rl;
        float ir = accI[rt][u][0][r] + bir;
        float iz = accI[rt][u][1][r] + biz;
        float in_ = accI[rt][u][2][r] + bin;
        float hr = accH[rt][u][0][r] + bhr;
        float hz = accH[rt][u][1][r] + bhz;
        float hn = accH[rt][u][2][r] + bhn;
        float rr = sigmoidf_(ir + hr);
        float zz = sigmoidf_(iz + hz);
        float nn = tanhf(fmaf(rr, hn, in_));
        float xv = (row < n) ? bf2f(xb[(size_t)row * 128 + col]) : 0.f;
        hl[rl][col] = f2b(fmaf(zz, xv - nn, nn));
      }
    }
  }
  __syncthreads();

  // phase 2: hid = relu(h @ ginw1^T + gb1); wave covers cols [32w, 32w+32)
  v4f acc2[2][2];
#pragma unroll
  for (int rt = 0; rt < 2; rt++)
#pragma unroll
    for (int u = 0; u < 2; u++) acc2[rt][u] = {0.f, 0.f, 0.f, 0.f};

#pragma unroll
  for (int kc = 0; kc < 4; kc++) {
    v8s a0 = *reinterpret_cast<const v8s*>(&hl[n0][kc * 32 + quad * 8]);
    v8s a1 = *reinterpret_cast<const v8s*>(&hl[16 + n0][kc * 32 + quad * 8]);
#pragma unroll
    for (int u = 0; u < 2; u++) {
      int t = wave * 2 + u;
      v8s bf = *reinterpret_cast<const v8s*>(G1rp + (size_t)kc * 4096 + (size_t)t * 512 + (size_t)lane * 8);
      acc2[0][u] = __builtin_amdgcn_mfma_f32_16x16x32_bf16(a0, bf, acc2[0][u], 0, 0, 0);
      acc2[1][u] = __builtin_amdgcn_mfma_f32_16x16x32_bf16(a1, bf, acc2[1][u], 0, 0, 0);
    }
  }

#pragma unroll
  for (int rt = 0; rt < 2; rt++) {
#pragma unroll
    for (int u = 0; u < 2; u++) {
      int col = wave * 32 + u * 16 + n0;
      float b = gb1[col];
#pragma unroll
      for (int r = 0; r < 4; r++) {
        int row = m0 + rt * 16 + quad * 4 + r;
        if (row < n)
          hidout[(size_t)row * 128 + col] = f2b(fmaxf(acc2[rt][u][r] + b, 0.f));
      }
    }
  }
}

// ---------------- head: one thread per node, FLOAT32 output ----------------
template <int C>
__global__ void k_heads(const uint16_t* __restrict__ hh, const float* __restrict__ w2,
                        const float* __restrict__ b2,
                        float* __restrict__ out_log, float* __restrict__ out_soft,
                        int n) {
  int node = blockIdx.x * 256 + threadIdx.x;
  if (node >= n) return;
  const uint16_t* row = hh + (size_t)node * 128;
  float lg[C];
#pragma unroll
  for (int c = 0; c < C; c++) lg[c] = b2[c];
  for (int k = 0; k < 128; k++) {
    float xv = bf2f(row[k]);
#pragma unroll
    for (int c = 0; c < C; c++) lg[c] = fmaf(xv, w2[c * 128 + k], lg[c]);
  }
  float m = lg[0];
#pragma unroll
  for (int c = 1; c < C; c++) m = fmaxf(m, lg[c]);
  float s = 0.f;
  float e[C];
#pragma unroll
  for (int c = 0; c < C; c++) { e[c] = __expf(lg[c] - m); s += e[c]; }
  float ls = __logf(s);
  float inv = 1.f / s;
#pragma unroll
  for (int c = 0; c < C; c++) {
    out_log[(size_t)node * C + c] = lg[c] - m - ls;
    out_soft[(size_t)node * C + c] = e[c] * inv;
  }
}

// ---------------------------------------------------------------------------
extern "C" void kernel_launch(void* const* d_in, const int* in_sizes, int n_in,
                              void* d_out, int out_size, void* d_ws, size_t ws_size,
                              hipStream_t stream) {
  const int N = in_sizes[0] / 128;   // 100000
  const int E = in_sizes[2];         // 1600000

  static const int wn[18] = {16384, 128, 49152, 384, 49152, 384,
                             147456, 147456, 1152, 1152, 49152, 384,
                             256, 2, 768, 6, 2688, 21};
  CvtDesc cd;
  int off = 0;
  for (int i = 0; i < 18; i++) {
    cd.src[i] = d_in[3 + i];
    cd.off[i] = off;
    off += wn[i];
  }
  cd.off[18] = off;
  const int wtotal = off;  // 466077

  // ---- workspace bump allocator (~70 MB) ----
  char* p = (char*)d_ws;
  size_t used = 0;
  auto alloc = [&](size_t bytes) -> char* {
    char* r = p;
    size_t b = (bytes + 255) & ~(size_t)255;
    p += b;
    used += b;
    return r;
  };
  int*      flag   = (int*)alloc(256);
  float*    wbase  = (float*)alloc((size_t)wtotal * 4);
  uint16_t* wb16   = (uint16_t*)alloc((size_t)wtotal * 2);
  uint16_t* mmrp   = (uint16_t*)alloc((size_t)10 * 16384 * 2);      // repacked mm W
  uint16_t* grurp  = (uint16_t*)alloc((size_t)3 * 192 * 512 * 2);   // repacked gru W
  uint16_t* xb     = (uint16_t*)alloc((size_t)N * 128 * 2);
  uint16_t* aggb   = (uint16_t*)alloc((size_t)N * 128 * 2);         // agg / hid / headhid
  int*      deg    = (int*)alloc((size_t)N * 4);
  int*      rowptr = (int*)alloc((size_t)(N + 1) * 4);
  int*      cursor = (int*)alloc((size_t)N * 4);
  uint2*    epack  = (uint2*)alloc((size_t)E * 8);
  int*      bsum   = (int*)alloc(4096);

  // FLOAT32 output layout (elements): log0|log1|log2|soft0|soft1|soft2
  float* out = (float*)d_out;
  float* outlog[3]  = {out, out + 2 * (size_t)N, out + 8 * (size_t)N};
  float* outsoft[3] = {out + 29 * (size_t)N, out + 31 * (size_t)N, out + 37 * (size_t)N};

  if (used > ws_size) {
    k_zero_f<<<(out_size + 255) / 256, 256, 0, stream>>>(out, out_size);
    return;
  }

  float* b1f   = wbase + cd.off[1];
  float* ginb1 = wbase + cd.off[3];
  float* ginb2 = wbase + cd.off[5];
  float* bih   = wbase + cd.off[8];
  float* bhh   = wbase + cd.off[9];
  float* hb1   = wbase + cd.off[11];
  float* hw2_0 = wbase + cd.off[12];
  float* hb2_0 = wbase + cd.off[13];
  float* hw2_1 = wbase + cd.off[14];
  float* hb2_1 = wbase + cd.off[15];
  float* hw2_2 = wbase + cd.off[16];
  float* hb2_2 = wbase + cd.off[17];

  uint16_t* w1b   = wb16 + cd.off[0];
  uint16_t* ginw1b= wb16 + cd.off[2];
  uint16_t* ginw2b= wb16 + cd.off[4];
  uint16_t* wihb  = wb16 + cd.off[6];
  uint16_t* whhb  = wb16 + cd.off[7];
  uint16_t* hw1b  = wb16 + cd.off[10];

  uint16_t* w1rp    = mmrp;
  uint16_t* ginw1rp = mmrp + (size_t)1 * 16384;
  uint16_t* ginw2rp = mmrp + (size_t)4 * 16384;
  uint16_t* hw1rp   = mmrp + (size_t)7 * 16384;

  const int* dst = (const int*)d_in[1];       // edge_index[0]
  const int* src = (const int*)d_in[1] + E;   // edge_index[1]

  // ---- dtype probe + conversions + repack ----
  k_detect<<<1, 64, 0, stream>>>((const uint32_t*)d_in[0], flag);
  k_cvtw<<<(wtotal + 255) / 256, 256, 0, stream>>>(cd, wbase, wb16, flag, wtotal);
  k_cvt_feat<<<((size_t)N * 128 + 255) / 256, 256, 0, stream>>>(d_in[0], aggb,
                                                                N * 128, flag);
  k_pack_mm<<<(1 * 2048 + 255) / 256, 256, 0, stream>>>(w1b, w1rp, 1);
  k_pack_mm<<<(3 * 2048 + 255) / 256, 256, 0, stream>>>(ginw1b, ginw1rp, 3);
  k_pack_mm<<<(3 * 2048 + 255) / 256, 256, 0, stream>>>(ginw2b, ginw2rp, 3);
  k_pack_mm<<<(3 * 2048 + 255) / 256, 256, 0, stream>>>(hw1b, hw1rp, 3);
  k_pack_gru<<<(3 * 192 * 64 + 255) / 256, 256, 0, stream>>>(wihb, whhb, grurp, 3);

  // ---- CSR build ----
  k_zero_i<<<(N + 255) / 256, 256, 0, stream>>>(deg, N);
  k_hist<<<(E + 255) / 256, 256, 0, stream>>>(dst, deg, E);
  int nb = (N + 1023) / 1024;
  k_scan1<<<nb, 256, 0, stream>>>(deg, bsum, N);
  k_scan2<<<1, 64, 0, stream>>>(bsum, nb, rowptr, N);
  k_scan3<<<nb, 256, 0, stream>>>(deg, bsum, rowptr, cursor, N);
  k_scatter<<<(E + 255) / 256, 256, 0, stream>>>(dst, src, d_in[2], cursor,
                                                 epack, flag, E);

  int mmrb = (N + 127) / 128;  // 128 rows/block (4 waves x 32)
  int grub = (N + 31) / 32;    // 32 rows/block
  int spb  = (N + 3) / 4;
  int hdb  = (N + 255) / 256;

  // mlp1: xb = relu(features(aggb) @ w1^T + b1)
  k_mm<1><<<mmrb, 256, 0, stream>>>(aggb, w1rp, b1f, xb, N);

  for (int i = 0; i < 3; i++) {
    // aggb = spmm(xb)
    k_spmm<<<spb, 256, 0, stream>>>(xb, rowptr, epack, aggb, N);
    // aggb = relu(GRU(aggb, xb) @ ginw1^T + ginb1)   [fused, h stays in LDS]
    k_grug<<<grub, 256, 0, stream>>>(aggb, xb, grurp + (size_t)i * 192 * 512,
                                     ginw1rp + (size_t)i * 16384,
                                     bih + i * 384, bhh + i * 384,
                                     ginb1 + i * 128, aggb, N);
    // xb = norm(relu(aggb @ ginw2^T + ginb2))
    k_mm<2><<<mmrb, 256, 0, stream>>>(aggb, ginw2rp + (size_t)i * 16384,
                                      ginb2 + i * 128, xb, N);
    // aggb = relu(xb @ hw1^T + hb1)
    k_mm<1><<<mmrb, 256, 0, stream>>>(xb, hw1rp + (size_t)i * 16384,
                                      hb1 + i * 128, aggb, N);
    if (i == 0)
      k_heads<2><<<hdb, 256, 0, stream>>>(aggb, hw2_0, hb2_0, outlog[0], outsoft[0], N);
    else if (i == 1)
      k_heads<6><<<hdb, 256, 0, stream>>>(aggb, hw2_1, hb2_1, outlog[1], outsoft[1], N);
    else
      k_heads<21><<<hdb, 256, 0, stream>>>(aggb, hw2_2, hb2_2, outlog[2], outsoft[2], N);
  }
}